// Round 1
// 1243.736 us; speedup vs baseline: 1.6008x; 1.6008x over previous
//
#include <hip/hip_runtime.h>

typedef unsigned short u16;
typedef unsigned int   u32;
typedef _Float16       f16;
typedef _Float16 f16x8 __attribute__((ext_vector_type(8)));
typedef float    f32x4 __attribute__((ext_vector_type(4)));

#define B_  64
#define T_  300
#define V_  25
#define C_  64
#define ROWS (B_*T_)          // 19200
#define ROWE (V_*C_)          // 1600
#define NSTAT 480000.0f       // B*T*V
#define EPS_ 1e-5f
#define TTILE 30              // k4_write time tile (10 tiles of 30)
#define K2GRID 4800           // k2 blocks (4 rows each)

__device__ __forceinline__ float b2f(u16 u) {
    union { u32 i; float f; } v; v.i = ((u32)u) << 16; return v.f;
}
__device__ __forceinline__ u16 f2b(float f) {  // round-to-nearest-even
    union { float f; u32 i; } v; v.f = f;
    u32 x = v.i;
    u32 r = x + 0x7fffu + ((x >> 16) & 1u);
    return (u16)(r >> 16);
}
__device__ __forceinline__ u32 pk2h(float a, float b) {   // pack 2 f32 -> 2 f16
    union { f16 h[2]; u32 u; } p;
    p.h[0] = (f16)a; p.h[1] = (f16)b;
    return p.u;
}
__device__ __forceinline__ u16 h2u(float v) {             // f32 -> f16 bits
    union { f16 h; u16 u; } p; p.h = (f16)v; return p.u;
}

// dtype-adaptive input load: F32 -> reinterpret as float*, else bf16 u16.
template<bool F32>
__device__ __forceinline__ float ldv(const void* p, size_t i) {
    if (F32) return ((const float*)p)[i];
    return b2f(((const u16*)p)[i]);
}

// out1 staging row stride in u16 units (fp32 mode: staging row r sits in the
// low half of fp32 output row r's byte range -> in-place overwrite is safe).
template<bool F32> struct Geo { static const int STR = F32 ? 3200 : 1600; };

// ---------------------------------------------------------------------------
// K0: dtype detection. Read W1's first 4096 u16 as bf16; fp32 data's low
// halves have uniform exponent bits -> max blows past 1e10 w.p. ~1.
// ---------------------------------------------------------------------------
__global__ void k0_detect(const void* W1raw, int* flag)
{
    __shared__ float red[256];
    const u16* p = (const u16*)W1raw;
    float mx = 0.0f;
    for (int i = threadIdx.x; i < 4096; i += 256) {
        float v = fabsf(b2f(p[i]));
        if (v == v) mx = fmaxf(mx, v);   // ignore NaN patterns
    }
    red[threadIdx.x] = mx;
    __syncthreads();
    for (int s = 128; s > 0; s >>= 1) {
        if (threadIdx.x < s) red[threadIdx.x] = fmaxf(red[threadIdx.x], red[threadIdx.x + s]);
        __syncthreads();
    }
    if (threadIdx.x == 0) flag[0] = (red[0] > 1e10f) ? 1 : 0;
}

// ---------------------------------------------------------------------------
// K1: prep for MFMA spatial stage.
//   anf  : An^T fragments, per-lane layout for mfma_16x16x32_f16 B-operand.
//          anf[((i*2+nt)*64 + lane)*8 + j] = An_i[v][u], v=nt*16+(lane&15),
//          u=(lane>>4)*8+j, zero outside 25x25.           (3072 f16)
//   wcatT: transposed weights, wcatT[i][c][k(pad 72)] = W_i[k][c]. (13824 f16)
//   bsum : b1+b2+b3.
// ---------------------------------------------------------------------------
template<bool F32>
__global__ void k1_prep(const int* __restrict__ flag,
                        const void* A, const void* E,
                        const void* W1, const void* W2, const void* W3,
                        const void* b1, const void* b2, const void* b3,
                        u16* __restrict__ anf, u16* __restrict__ wcatT,
                        float* __restrict__ bsum)
{
    if (flag[0] != (F32 ? 1 : 0)) return;
    __shared__ float dinvL[75];
    const int tid = threadIdx.x;
    if (tid < 75) {
        int i = tid / 25, v = tid % 25;
        float d = 1.0f;                       // diagonal forced to 1
        for (int u = 0; u < 25; ++u)
            if (u != v) d += ldv<F32>(A, (i*25+v)*25+u) * ldv<F32>(E, (i*25+v)*25+u);
        dinvL[tid] = (d > 0.0f) ? rsqrtf(d) : 0.0f;
    }
    __syncthreads();
    // An^T fragments
    for (int idx = tid; idx < 3072; idx += 256) {
        int fr = idx >> 9, lane = (idx >> 3) & 63, j = idx & 7;
        int i = fr >> 1, nt = fr & 1;
        int v = nt*16 + (lane & 15);
        int u = ((lane >> 4) << 3) + j;
        float val = 0.0f;
        if (v < 25 && u < 25) {
            float ad = (u == v) ? 1.0f
                     : ldv<F32>(A, (i*25+v)*25+u) * ldv<F32>(E, (i*25+v)*25+u);
            val = dinvL[i*25+v] * ad * dinvL[i*25+u];
        }
        anf[idx] = h2u(val);
    }
    // WcatT[i][c][k] = W_i[k][c], rows padded to 72 halfs (16B-aligned rows)
    for (int idx = tid; idx < 13824; idx += 256) {
        int i = idx / 4608;
        int rem = idx - i*4608;
        int c = rem / 72, k = rem - (rem/72)*72;
        float val = 0.0f;
        if (k < 64) {
            const void* W = (i == 0) ? W1 : ((i == 1) ? W2 : W3);
            val = ldv<F32>(W, k*64 + c);
        }
        wcatT[idx] = h2u(val);
    }
    if (tid < 64) bsum[tid] = ldv<F32>(b1, tid) + ldv<F32>(b2, tid) + ldv<F32>(b3, tid);
}

// ---------------------------------------------------------------------------
// K2 (MFMA): spatial block. 4 rows (b,t) per block, grid 4800.
//   phase 1 (per branch i): xw[(r,u)][c] = x_r @ W_i   via mfma 16x16x32 f16
//     M=(r,u) flat, u padded to 28 -> M=112=7 exact tiles, K=64, N=64.
//   phase 2 (per branch i): acc[(r,c)][v] += xw @ An_i^T
//     M=(r,c) flat=256=16 exact tiles, K=u pad 32, N=v pad 32; An frags in regs.
//   epilogue: +bsum, BN1 partials (shuffle-reduced), bf16 out1 (ushort4 stores).
// ---------------------------------------------------------------------------
template<bool F32>
__global__ __launch_bounds__(256, 3) void k2_mfma(
    const int* __restrict__ flag, const void* x,
    const u16* __restrict__ wcatT, const u16* __restrict__ anf,
    const float* __restrict__ bsum,
    u16* __restrict__ out1, float* __restrict__ p1)
{
    if (flag[0] != (F32 ? 1 : 0)) return;
    const int STR = Geo<F32>::STR;

    __shared__ f16 xf[112*72];     // x tile, [m=r*28+u][72], 16.1 KB
    __shared__ u16 xw[256*40];     // xw tile, [m2=r*64+c][40], 20.5 KB

    const int tid  = threadIdx.x;
    const int lane = tid & 63, w = tid >> 6;
    const int r0   = blockIdx.x * 4;

    // ---- stage x (4 rows) as f16 into xf ----
    for (int q4 = tid; q4 < 1600; q4 += 256) {
        int r = (q4 * 10486) >> 22;          // q4/400
        int rem = q4 - 400*r;
        float v0, v1, v2, v3;
        if (F32) {
            float4 t4 = ((const float4*)x)[(size_t)(r0+r)*400 + rem];
            v0 = t4.x; v1 = t4.y; v2 = t4.z; v3 = t4.w;
        } else {
            ushort4 t4 = ((const ushort4*)x)[(size_t)(r0+r)*400 + rem];
            v0 = b2f(t4.x); v1 = b2f(t4.y); v2 = b2f(t4.z); v3 = b2f(t4.w);
        }
        int u = rem >> 4, k0 = (rem & 15) << 2;
        int m = r*28 + u;
        *(uint2*)&xf[m*72 + k0] = make_uint2(pk2h(v0, v1), pk2h(v2, v3));
    }
    // zero x pad rows u=25..27 (12 rows x 72 halfs = 432 u32)
    for (int idx = tid; idx < 432; idx += 256) {
        int j  = (idx * 57) >> 11;           // idx/36
        int off = idx - 36*j;
        int rr = (j*11) >> 5, p = j - 3*rr;  // j/3
        ((u32*)xf)[(rr*28 + 25 + p)*36 + off] = 0u;
    }
    // zero xw u-pad [28,32) so phase-2 K-pad multiplies 0 (not junk/NaN)
    *(uint2*)&xw[tid*40 + 28] = make_uint2(0u, 0u);

    // ---- preload An^T fragments + bias ----
    f16x8 anfr[3][2];
    #pragma unroll
    for (int i = 0; i < 3; ++i)
        #pragma unroll
        for (int nt = 0; nt < 2; ++nt)
            anfr[i][nt] = *(const f16x8*)&anf[((i*2 + nt)*64 + lane)*8];

    const int c0 = w*16 + ((lane >> 4) << 2);   // this thread's 4 channels
    float bs[4];
    #pragma unroll
    for (int t = 0; t < 4; ++t) bs[t] = bsum[c0 + t];

    f32x4 acc[4][2];
    #pragma unroll
    for (int j = 0; j < 4; ++j) {
        acc[j][0] = f32x4{0.f, 0.f, 0.f, 0.f};
        acc[j][1] = f32x4{0.f, 0.f, 0.f, 0.f};
    }

    __syncthreads();

    #pragma unroll
    for (int i = 0; i < 3; ++i) {
        // W fragments for this branch (B-operand), from global (L2-hot)
        f16x8 wfr[4][2];
        #pragma unroll
        for (int nt = 0; nt < 4; ++nt)
            #pragma unroll
            for (int ks = 0; ks < 2; ++ks)
                wfr[nt][ks] = *(const f16x8*)&wcatT[
                    (i*64 + nt*16 + (lane & 15))*72 + ks*32 + ((lane >> 4) << 3)];

        // ---- phase 1: xw = x @ W_i ----
        for (int mt = w; mt < 7; mt += 4) {
            const int arow = (mt*16 + (lane & 15))*72 + ((lane >> 4) << 3);
            f16x8 a0 = *(const f16x8*)&xf[arow];
            f16x8 a1 = *(const f16x8*)&xf[arow + 32];
            const int m0 = mt*16 + ((lane >> 4) << 2);
            const int r  = (m0 * 293) >> 13;        // m0/28
            const int u0 = m0 - 28*r;
            #pragma unroll
            for (int nt = 0; nt < 4; ++nt) {
                f32x4 d = f32x4{0.f, 0.f, 0.f, 0.f};
                d = __builtin_amdgcn_mfma_f32_16x16x32_f16(a0, wfr[nt][0], d, 0, 0, 0);
                d = __builtin_amdgcn_mfma_f32_16x16x32_f16(a1, wfr[nt][1], d, 0, 0, 0);
                const int cc = nt*16 + (lane & 15);
                *(uint2*)&xw[(r*64 + cc)*40 + u0] =
                    make_uint2(pk2h(d[0], d[1]), pk2h(d[2], d[3]));
            }
        }
        __syncthreads();

        // ---- phase 2: acc += xw @ An_i^T ----
        #pragma unroll
        for (int j = 0; j < 4; ++j) {
            const int mt2 = w + 4*j;
            f16x8 a = *(const f16x8*)&xw[(mt2*16 + (lane & 15))*40 + ((lane >> 4) << 3)];
            acc[j][0] = __builtin_amdgcn_mfma_f32_16x16x32_f16(a, anfr[i][0], acc[j][0], 0, 0, 0);
            acc[j][1] = __builtin_amdgcn_mfma_f32_16x16x32_f16(a, anfr[i][1], acc[j][1], 0, 0, 0);
        }
        __syncthreads();
    }

    // ---- epilogue: bias, BN1 partials, bf16 store ----
    float ssum[4] = {0.f, 0.f, 0.f, 0.f}, ssq[4] = {0.f, 0.f, 0.f, 0.f};
    const int vb = lane & 15;
    #pragma unroll
    for (int j = 0; j < 4; ++j) {          // rloc = j (mt2>>2)
        #pragma unroll
        for (int nt = 0; nt < 2; ++nt) {
            const int v = nt*16 + vb;
            if (v < 25) {
                float o0 = acc[j][nt][0] + bs[0];
                float o1 = acc[j][nt][1] + bs[1];
                float o2 = acc[j][nt][2] + bs[2];
                float o3 = acc[j][nt][3] + bs[3];
                ssum[0] += o0; ssq[0] += o0*o0;
                ssum[1] += o1; ssq[1] += o1*o1;
                ssum[2] += o2; ssq[2] += o2*o2;
                ssum[3] += o3; ssq[3] += o3*o3;
                ushort4 pk;
                pk.x = f2b(o0); pk.y = f2b(o1); pk.z = f2b(o2); pk.w = f2b(o3);
                *(ushort4*)&out1[(size_t)(r0 + j)*STR + v*64 + c0] = pk;
            }
        }
    }
    #pragma unroll
    for (int t = 0; t < 4; ++t) {
        #pragma unroll
        for (int off = 1; off < 16; off <<= 1) {
            ssum[t] += __shfl_xor(ssum[t], off);
            ssq[t]  += __shfl_xor(ssq[t],  off);
        }
    }
    if ((lane & 15) == 0) {
        #pragma unroll
        for (int t = 0; t < 4; ++t) {
            p1[(size_t)blockIdx.x*128 + c0 + t]      = ssum[t];
            p1[(size_t)blockIdx.x*128 + 64 + c0 + t] = ssq[t];
        }
    }
}

// ---------------------------------------------------------------------------
// K3/K5: finalize BN stats -> scale/shift per channel (1024 threads)
// ---------------------------------------------------------------------------
template<bool F32>
__global__ void k_bnstats(const int* __restrict__ flag,
                          const float* __restrict__ part, int nblk,
                          const void* gamma, const void* beta,
                          float* __restrict__ scale, float* __restrict__ shift)
{
    if (flag[0] != (F32 ? 1 : 0)) return;
    __shared__ float redL[2048];
    const int tid = threadIdx.x, c = tid & 63, q = tid >> 6;   // q < 16
    float s = 0.0f, ss = 0.0f;
    for (int p = q; p < nblk; p += 16) { s += part[p*128 + c]; ss += part[p*128 + 64 + c]; }
    redL[q*64 + c] = s; redL[1024 + q*64 + c] = ss;
    __syncthreads();
    for (int h = 8; h > 0; h >>= 1) {
        if (q < h) {
            redL[q*64 + c]        += redL[(q+h)*64 + c];
            redL[1024 + q*64 + c] += redL[1024 + (q+h)*64 + c];
        }
        __syncthreads();
    }
    if (tid < 64) {
        const float S  = redL[tid];
        const float SS = redL[1024 + tid];
        const float m   = S / NSTAT;
        const float var = SS / NSTAT - m*m;
        const float rstd = rsqrtf(var + EPS_);
        const float sc = ldv<F32>(gamma, tid) * rstd;
        scale[tid] = sc;
        shift[tid] = ldv<F32>(beta, tid) - m * sc;
    }
}

// ---------------------------------------------------------------------------
// K_halo: save boundary out1 rows (t%30 in {0..3, 26..29}) into ws so the
// in-place k4_write pass can read cross-tile halos after neighbors overwrite.
// ---------------------------------------------------------------------------
template<bool F32>
__global__ __launch_bounds__(128) void k_halo(const int* __restrict__ flag,
                                              const u16* out1, u16* halo)
{
    if (flag[0] != (F32 ? 1 : 0)) return;
    const int STR = Geo<F32>::STR;
    const int id = blockIdx.x;            // 64*10*8 = 5120
    const int slot = id & 7, tile = (id >> 3) % 10, b = id / 80;
    const int t = tile * TTILE + (slot < 4 ? slot : slot + 22);
    const uint4* src = (const uint4*)&out1[((size_t)b*T_ + t) * STR];
    uint4* dst = (uint4*)&halo[(size_t)id * ROWE];
    for (int j = threadIdx.x; j < 200; j += 128) dst[j] = src[j];
}

template<bool F32>
__device__ __forceinline__ const u16* row_ptr(const u16* out1, const u16* halo,
                                              int b, int s, int t0)
{
    if (s >= t0 && s < t0 + TTILE)
        return &out1[((size_t)b*T_ + s) * Geo<F32>::STR];
    const int tile = s / TTILE, rem = s % TTILE;
    const int slot = rem < 4 ? rem : rem - 22;
    return &halo[(((size_t)b*10 + tile)*8 + slot) * ROWE];
}

// ---------------------------------------------------------------------------
// K4a (stats): h = relu(bn1(out1)); sliding band-sum; z = hsum@Wt + bt;
// accumulate BN2 partials ONLY (no z store).
// ---------------------------------------------------------------------------
template<bool F32>
__global__ __launch_bounds__(256) void k4_stats(
    const int* __restrict__ flag,
    const u16* out1, const void* Wt, const void* bt,
    const float* __restrict__ sc1, const float* __restrict__ sh1,
    float* __restrict__ p2)
{
    if (flag[0] != (F32 ? 1 : 0)) return;
    const int STR = Geo<F32>::STR;

    __shared__ u16   ring[10*1600];
    __shared__ float haccL[1600];
    __shared__ float wtL[4096];
    __shared__ float redL[512];

    const int tid = threadIdx.x, c = tid & 63, g = tid >> 6;
    const int b = blockIdx.y, t0 = blockIdx.x * 15;
    const float s1 = sc1[c], h1 = sh1[c];
    const float btv = ldv<F32>(bt, c);

    for (int i2 = tid; i2 < 4096; i2 += 256) wtL[i2] = ldv<F32>(Wt, i2);
    for (int i2 = tid; i2 < 1600; i2 += 256) haccL[i2] = 0.0f;
    __syncthreads();

    float zsum = 0.0f, zsq = 0.0f;

    {   // initial window [t0-4, t0+4]
        int slo = t0 - 4; if (slo < 0) slo = 0;
        const int shi = t0 + 4;            // <= 289
        for (int s = slo; s <= shi; ++s) {
            const u16* xr = &out1[((size_t)b*T_ + s) * STR];
            for (int jj = tid; jj < 1600; jj += 256) {   // jj&63 == c
                float hv = fmaf(b2f(xr[jj]), s1, h1);
                hv = hv > 0.0f ? hv : 0.0f;
                const u16 hb = f2b(hv);
                ring[(s%10)*1600 + jj] = hb;
                haccL[jj] += b2f(hb);
            }
        }
    }
    __syncthreads();

    for (int t = t0; t < t0 + 15; ++t) {
        if (t > t0) {
            const int snew = t + 4, sold = t - 5;
            if (snew < T_) {
                const u16* xr = &out1[((size_t)b*T_ + snew) * STR];
                for (int jj = tid; jj < 1600; jj += 256) {
                    float hv = fmaf(b2f(xr[jj]), s1, h1);
                    hv = hv > 0.0f ? hv : 0.0f;
                    const u16 hb = f2b(hv);
                    ring[(snew%10)*1600 + jj] = hb;
                    haccL[jj] += b2f(hb);
                }
            }
            if (sold >= 0) {
                for (int jj = tid; jj < 1600; jj += 256)
                    haccL[jj] -= b2f(ring[(sold%10)*1600 + jj]);
            }
            __syncthreads();
        }

        float acc[7];
        #pragma unroll
        for (int j = 0; j < 7; ++j) acc[j] = btv;
        #pragma unroll 4
        for (int k4 = 0; k4 < 16; ++k4) {
            const int k = k4 * 4;
            const float w0 = wtL[(k+0)*64+c], w1 = wtL[(k+1)*64+c];
            const float w2 = wtL[(k+2)*64+c], w3 = wtL[(k+3)*64+c];
            #pragma unroll
            for (int j = 0; j < 7; ++j) {
                const int v = g + 4*j;
                if (v < 25) {
                    const float4 hv4 = *(const float4*)&haccL[v*64+k];
                    acc[j] = fmaf(hv4.x, w0, fmaf(hv4.y, w1,
                             fmaf(hv4.z, w2, fmaf(hv4.w, w3, acc[j]))));
                }
            }
        }
        #pragma unroll
        for (int j = 0; j < 7; ++j) {
            const int v = g + 4*j;
            if (v < 25) { const float zz = acc[j]; zsum += zz; zsq += zz * zz; }
        }
        __syncthreads();   // hacc reads done before next window update
    }

    redL[g*64+c] = zsum; redL[256+g*64+c] = zsq;
    __syncthreads();
    const int blk = blockIdx.y * 20 + blockIdx.x;
    if (tid < 64) {
        float s = redL[tid] + redL[64+tid] + redL[128+tid] + redL[192+tid];
        p2[(size_t)blk*128 + tid] = s;
    } else if (tid < 128) {
        const int cc = tid - 64;
        float s = redL[256+cc] + redL[320+cc] + redL[384+cc] + redL[448+cc];
        p2[(size_t)blk*128 + 64 + cc] = s;
    }
}

// ---------------------------------------------------------------------------
// K4b (write): recompute z, apply bn2+relu, write final output to d_out IN
// PLACE over the staging (bf16 mode: same rows; fp32 mode: fp32 row r's bytes
// cover staging row r exactly). Cross-tile halo rows come from ws copy.
// Within a tile, row t is written >=4 barriers after its last staging read.
// ---------------------------------------------------------------------------
template<bool F32>
__global__ __launch_bounds__(256) void k4_write(
    const int* __restrict__ flag,
    const u16* out1, const u16* halo,
    const void* Wt, const void* bt,
    const float* __restrict__ sc1, const float* __restrict__ sh1,
    const float* __restrict__ sc2, const float* __restrict__ sh2,
    void* outp)
{
    if (flag[0] != (F32 ? 1 : 0)) return;

    __shared__ u16   ring[10*1600];
    __shared__ float haccL[1600];
    __shared__ float wtL[4096];

    const int tid = threadIdx.x, c = tid & 63, g = tid >> 6;
    const int b = blockIdx.y, t0 = blockIdx.x * TTILE;
    const float s1 = sc1[c], h1 = sh1[c];
    const float s2 = sc2[c], h2 = sh2[c];
    const float btv = ldv<F32>(bt, c);

    for (int i2 = tid; i2 < 4096; i2 += 256) wtL[i2] = ldv<F32>(Wt, i2);
    for (int i2 = tid; i2 < 1600; i2 += 256) haccL[i2] = 0.0f;
    __syncthreads();

    {   // initial window [t0-4, t0+4]
        int slo = t0 - 4; if (slo < 0) slo = 0;
        const int shi = t0 + 4;
        for (int s = slo; s <= shi; ++s) {
            const u16* xr = row_ptr<F32>(out1, halo, b, s, t0);
            for (int jj = tid; jj < 1600; jj += 256) {
                float hv = fmaf(b2f(xr[jj]), s1, h1);
                hv = hv > 0.0f ? hv : 0.0f;
                const u16 hb = f2b(hv);
                ring[(s%10)*1600 + jj] = hb;
                haccL[jj] += b2f(hb);
            }
        }
    }
    __syncthreads();

    for (int t = t0; t < t0 + TTILE; ++t) {
        if (t > t0) {
            const int snew = t + 4, sold = t - 5;
            if (snew < T_) {
                const u16* xr = row_ptr<F32>(out1, halo, b, snew, t0);
                for (int jj = tid; jj < 1600; jj += 256) {
                    float hv = fmaf(b2f(xr[jj]), s1, h1);
                    hv = hv > 0.0f ? hv : 0.0f;
                    const u16 hb = f2b(hv);
                    ring[(snew%10)*1600 + jj] = hb;
                    haccL[jj] += b2f(hb);
                }
            }
            if (sold >= 0) {
                for (int jj = tid; jj < 1600; jj += 256)
                    haccL[jj] -= b2f(ring[(sold%10)*1600 + jj]);
            }
            __syncthreads();
        }

        float acc[7];
        #pragma unroll
        for (int j = 0; j < 7; ++j) acc[j] = btv;
        #pragma unroll 4
        for (int k4 = 0; k4 < 16; ++k4) {
            const int k = k4 * 4;
            const float w0 = wtL[(k+0)*64+c], w1 = wtL[(k+1)*64+c];
            const float w2 = wtL[(k+2)*64+c], w3 = wtL[(k+3)*64+c];
            #pragma unroll
            for (int j = 0; j < 7; ++j) {
                const int v = g + 4*j;
                if (v < 25) {
                    const float4 hv4 = *(const float4*)&haccL[v*64+k];
                    acc[j] = fmaf(hv4.x, w0, fmaf(hv4.y, w1,
                             fmaf(hv4.z, w2, fmaf(hv4.w, w3, acc[j]))));
                }
            }
        }
        const size_t rowbase = ((size_t)b*T_ + t) * ROWE;
        #pragma unroll
        for (int j = 0; j < 7; ++j) {
            const int v = g + 4*j;
            if (v < 25) {
                float o = fmaf(acc[j], s2, h2);
                o = o > 0.0f ? o : 0.0f;
                if (F32) ((float*)outp)[rowbase + v*64 + c] = o;
                else     ((u16*)outp)[rowbase + v*64 + c] = f2b(o);
            }
        }
        __syncthreads();   // staging/hacc reads done before next update
    }
}

// ---------------------------------------------------------------------------
extern "C" void kernel_launch(void* const* d_in, const int* in_sizes, int n_in,
                              void* d_out, int out_size, void* d_ws, size_t ws_size,
                              hipStream_t stream)
{
    const void* x     = d_in[0];
    const void* A     = d_in[1];
    const void* E     = d_in[2];
    const void* W1    = d_in[3];
    const void* b1    = d_in[4];
    const void* W2    = d_in[5];
    const void* b2    = d_in[6];
    const void* W3    = d_in[7];
    const void* b3    = d_in[8];
    const void* Wt    = d_in[9];
    const void* bt    = d_in[10];
    const void* gamma = d_in[11];
    const void* beta  = d_in[12];

    u16* out1 = (u16*)d_out;          // stage-1 bf16 staging lives in d_out

    // ws layout — front of d_ws; total ≈ 19.5 MB.
    int*   flag = (int*)d_ws;
    float* wsf  = (float*)d_ws;
    float* bsum = wsf + 4;
    float* sc1  = bsum + 64;
    float* sh1  = sc1 + 64;
    float* sc2  = sh1 + 64;
    float* sh2  = sc2 + 64;
    float* p1   = sh2 + 64;                       // K2GRID*128
    float* p2   = p1 + (size_t)K2GRID*128;        // 1280*128
    u16*  halo  = (u16*)(p2 + 1280*128);          // 5120*1600 u16 = 16.4 MB
    u16*  wcatT = halo + (size_t)5120*1600;       // 13824 f16
    u16*  anf   = wcatT + 13824;                  // 3072 f16

    hipLaunchKernelGGL(k0_detect, dim3(1), dim3(256), 0, stream, W1, flag);

    hipLaunchKernelGGL(k1_prep<false>, dim3(1), dim3(256), 0, stream,
                       flag, A, E, W1, W2, W3, b1, b2, b3, anf, wcatT, bsum);
    hipLaunchKernelGGL(k1_prep<true>, dim3(1), dim3(256), 0, stream,
                       flag, A, E, W1, W2, W3, b1, b2, b3, anf, wcatT, bsum);

    hipLaunchKernelGGL(k2_mfma<false>, dim3(K2GRID), dim3(256), 0, stream,
                       flag, x, wcatT, anf, bsum, out1, p1);
    hipLaunchKernelGGL(k2_mfma<true>, dim3(K2GRID), dim3(256), 0, stream,
                       flag, x, wcatT, anf, bsum, out1, p1);

    hipLaunchKernelGGL(k_bnstats<false>, dim3(1), dim3(1024), 0, stream,
                       flag, p1, K2GRID, gamma, beta, sc1, sh1);
    hipLaunchKernelGGL(k_bnstats<true>, dim3(1), dim3(1024), 0, stream,
                       flag, p1, K2GRID, gamma, beta, sc1, sh1);

    hipLaunchKernelGGL(k_halo<false>, dim3(5120), dim3(128), 0, stream,
                       flag, out1, halo);
    hipLaunchKernelGGL(k_halo<true>, dim3(5120), dim3(128), 0, stream,
                       flag, out1, halo);

    hipLaunchKernelGGL(k4_stats<false>, dim3(20, 64), dim3(256), 0, stream,
                       flag, out1, Wt, bt, sc1, sh1, p2);
    hipLaunchKernelGGL(k4_stats<true>, dim3(20, 64), dim3(256), 0, stream,
                       flag, out1, Wt, bt, sc1, sh1, p2);

    hipLaunchKernelGGL(k_bnstats<false>, dim3(1), dim3(1024), 0, stream,
                       flag, p2, 1280, gamma, beta, sc2, sh2);
    hipLaunchKernelGGL(k_bnstats<true>, dim3(1), dim3(1024), 0, stream,
                       flag, p2, 1280, gamma, beta, sc2, sh2);

    hipLaunchKernelGGL(k4_write<false>, dim3(10, 64), dim3(256), 0, stream,
                       flag, out1, halo, Wt, bt, sc1, sh1, sc2, sh2, d_out);
    hipLaunchKernelGGL(k4_write<true>, dim3(10, 64), dim3(256), 0, stream,
                       flag, out1, halo, Wt, bt, sc1, sh1, sc2, sh2, d_out);
}

// Round 2
// 491.861 us; speedup vs baseline: 4.0478x; 2.5286x over previous
//
#include <hip/hip_runtime.h>

typedef unsigned short u16;
typedef unsigned int   u32;
typedef _Float16       f16;
typedef _Float16 f16x8 __attribute__((ext_vector_type(8)));
typedef float    f32x4 __attribute__((ext_vector_type(4)));

#define B_  64
#define T_  300
#define V_  25
#define C_  64
#define ROWS (B_*T_)          // 19200
#define ROWE (V_*C_)          // 1600
#define NSTAT 480000.0f       // B*T*V
#define EPS_ 1e-5f
#define TTILE 30              // temporal tile (10 tiles of 30)
#define K2GRID 4800           // k2 blocks (4 rows each)

__device__ __forceinline__ float b2f(u16 u) {
    union { u32 i; float f; } v; v.i = ((u32)u) << 16; return v.f;
}
__device__ __forceinline__ u16 f2b(float f) {  // round-to-nearest-even
    union { float f; u32 i; } v; v.f = f;
    u32 x = v.i;
    u32 r = x + 0x7fffu + ((x >> 16) & 1u);
    return (u16)(r >> 16);
}
__device__ __forceinline__ u32 pk2h(float a, float b) {   // pack 2 f32 -> 2 f16
    union { f16 h[2]; u32 u; } p;
    p.h[0] = (f16)a; p.h[1] = (f16)b;
    return p.u;
}
__device__ __forceinline__ u16 h2u(float v) {             // f32 -> f16 bits
    union { f16 h; u16 u; } p; p.h = (f16)v; return p.u;
}
__device__ __forceinline__ float u2h(u16 u) {             // f16 bits -> f32
    union { u16 u; f16 h; } p; p.u = u; return (float)p.h;
}

// dtype-adaptive input load: F32 -> reinterpret as float*, else bf16 u16.
template<bool F32>
__device__ __forceinline__ float ldv(const void* p, size_t i) {
    if (F32) return ((const float*)p)[i];
    return b2f(((const u16*)p)[i]);
}

// staging row stride in u16 units (fp32 mode: staging row r sits in the
// low half of fp32 output row r's byte range -> in-place overwrite is safe).
template<bool F32> struct Geo { static const int STR = F32 ? 3200 : 1600; };

// ---------------------------------------------------------------------------
// K0: dtype detection. Read W1's first 4096 u16 as bf16; fp32 data's low
// halves have uniform exponent bits -> max blows past 1e10 w.p. ~1.
// ---------------------------------------------------------------------------
__global__ void k0_detect(const void* W1raw, int* flag)
{
    __shared__ float red[256];
    const u16* p = (const u16*)W1raw;
    float mx = 0.0f;
    for (int i = threadIdx.x; i < 4096; i += 256) {
        float v = fabsf(b2f(p[i]));
        if (v == v) mx = fmaxf(mx, v);   // ignore NaN patterns
    }
    red[threadIdx.x] = mx;
    __syncthreads();
    for (int s = 128; s > 0; s >>= 1) {
        if (threadIdx.x < s) red[threadIdx.x] = fmaxf(red[threadIdx.x], red[threadIdx.x + s]);
        __syncthreads();
    }
    if (threadIdx.x == 0) flag[0] = (red[0] > 1e10f) ? 1 : 0;
}

// ---------------------------------------------------------------------------
// K1: prep tables.
//   anf  : An^T fragments (k2 phase-2 B-operand), 3072 f16.
//   wcatT: wcatT[i][c][k(pad 72)] = W_i[k][c], 13824 f16 (k2 phase-1 B).
//   wtT  : wtT[c][k(pad 72)] = Wt[k][c], 4608 f16 (k3 B-operand).
//   bsum : b1+b2+b3.
// ---------------------------------------------------------------------------
template<bool F32>
__global__ void k1_prep(const int* __restrict__ flag,
                        const void* A, const void* E,
                        const void* W1, const void* W2, const void* W3,
                        const void* Wt,
                        const void* b1, const void* b2, const void* b3,
                        u16* __restrict__ anf, u16* __restrict__ wcatT,
                        u16* __restrict__ wtT, float* __restrict__ bsum)
{
    if (flag[0] != (F32 ? 1 : 0)) return;
    __shared__ float dinvL[75];
    const int tid = threadIdx.x;
    if (tid < 75) {
        int i = tid / 25, v = tid % 25;
        float d = 1.0f;                       // diagonal forced to 1
        for (int u = 0; u < 25; ++u)
            if (u != v) d += ldv<F32>(A, (i*25+v)*25+u) * ldv<F32>(E, (i*25+v)*25+u);
        dinvL[tid] = (d > 0.0f) ? rsqrtf(d) : 0.0f;
    }
    __syncthreads();
    // An^T fragments
    for (int idx = tid; idx < 3072; idx += 256) {
        int fr = idx >> 9, lane = (idx >> 3) & 63, j = idx & 7;
        int i = fr >> 1, nt = fr & 1;
        int v = nt*16 + (lane & 15);
        int u = ((lane >> 4) << 3) + j;
        float val = 0.0f;
        if (v < 25 && u < 25) {
            float ad = (u == v) ? 1.0f
                     : ldv<F32>(A, (i*25+v)*25+u) * ldv<F32>(E, (i*25+v)*25+u);
            val = dinvL[i*25+v] * ad * dinvL[i*25+u];
        }
        anf[idx] = h2u(val);
    }
    // WcatT[i][c][k] = W_i[k][c], rows padded to 72 halfs
    for (int idx = tid; idx < 13824; idx += 256) {
        int i = idx / 4608;
        int rem = idx - i*4608;
        int c = rem / 72, k = rem - (rem/72)*72;
        float val = 0.0f;
        if (k < 64) {
            const void* W = (i == 0) ? W1 : ((i == 1) ? W2 : W3);
            val = ldv<F32>(W, k*64 + c);
        }
        wcatT[idx] = h2u(val);
    }
    // WtT[c][k] = Wt[k][c], rows padded to 72 halfs
    for (int idx = tid; idx < 4608; idx += 256) {
        int c = idx / 72, k = idx - (idx/72)*72;
        float val = (k < 64) ? ldv<F32>(Wt, k*64 + c) : 0.0f;
        wtT[idx] = h2u(val);
    }
    if (tid < 64) bsum[tid] = ldv<F32>(b1, tid) + ldv<F32>(b2, tid) + ldv<F32>(b3, tid);
}

// ---------------------------------------------------------------------------
// K2 (MFMA): spatial block. 4 rows (b,t) per block, grid 4800.
// ---------------------------------------------------------------------------
template<bool F32>
__global__ __launch_bounds__(256, 3) void k2_mfma(
    const int* __restrict__ flag, const void* x,
    const u16* __restrict__ wcatT, const u16* __restrict__ anf,
    const float* __restrict__ bsum,
    u16* __restrict__ out1, float* __restrict__ p1)
{
    if (flag[0] != (F32 ? 1 : 0)) return;
    const int STR = Geo<F32>::STR;

    __shared__ f16 xf[112*72];     // x tile, [m=r*28+u][72], 16.1 KB
    __shared__ u16 xw[256*40];     // xw tile, [m2=r*64+c][40], 20.5 KB

    const int tid  = threadIdx.x;
    const int lane = tid & 63, w = tid >> 6;
    const int r0   = blockIdx.x * 4;

    // ---- stage x (4 rows) as f16 into xf ----
    for (int q4 = tid; q4 < 1600; q4 += 256) {
        int r = (q4 * 10486) >> 22;          // q4/400
        int rem = q4 - 400*r;
        float v0, v1, v2, v3;
        if (F32) {
            float4 t4 = ((const float4*)x)[(size_t)(r0+r)*400 + rem];
            v0 = t4.x; v1 = t4.y; v2 = t4.z; v3 = t4.w;
        } else {
            ushort4 t4 = ((const ushort4*)x)[(size_t)(r0+r)*400 + rem];
            v0 = b2f(t4.x); v1 = b2f(t4.y); v2 = b2f(t4.z); v3 = b2f(t4.w);
        }
        int u = rem >> 4, k0 = (rem & 15) << 2;
        int m = r*28 + u;
        *(uint2*)&xf[m*72 + k0] = make_uint2(pk2h(v0, v1), pk2h(v2, v3));
    }
    // zero x pad rows u=25..27
    for (int idx = tid; idx < 432; idx += 256) {
        int j  = (idx * 57) >> 11;           // idx/36
        int off = idx - 36*j;
        int rr = (j*11) >> 5, p = j - 3*rr;  // j/3
        ((u32*)xf)[(rr*28 + 25 + p)*36 + off] = 0u;
    }
    // zero xw u-pad [28,32)
    *(uint2*)&xw[tid*40 + 28] = make_uint2(0u, 0u);

    // ---- preload An^T fragments + bias ----
    f16x8 anfr[3][2];
    #pragma unroll
    for (int i = 0; i < 3; ++i)
        #pragma unroll
        for (int nt = 0; nt < 2; ++nt)
            anfr[i][nt] = *(const f16x8*)&anf[((i*2 + nt)*64 + lane)*8];

    const int c0 = w*16 + ((lane >> 4) << 2);   // this thread's 4 channels
    float bs[4];
    #pragma unroll
    for (int t = 0; t < 4; ++t) bs[t] = bsum[c0 + t];

    f32x4 acc[4][2];
    #pragma unroll
    for (int j = 0; j < 4; ++j) {
        acc[j][0] = f32x4{0.f, 0.f, 0.f, 0.f};
        acc[j][1] = f32x4{0.f, 0.f, 0.f, 0.f};
    }

    __syncthreads();

    #pragma unroll
    for (int i = 0; i < 3; ++i) {
        f16x8 wfr[4][2];
        #pragma unroll
        for (int nt = 0; nt < 4; ++nt)
            #pragma unroll
            for (int ks = 0; ks < 2; ++ks)
                wfr[nt][ks] = *(const f16x8*)&wcatT[
                    (i*64 + nt*16 + (lane & 15))*72 + ks*32 + ((lane >> 4) << 3)];

        // ---- phase 1: xw = x @ W_i ----
        for (int mt = w; mt < 7; mt += 4) {
            const int arow = (mt*16 + (lane & 15))*72 + ((lane >> 4) << 3);
            f16x8 a0 = *(const f16x8*)&xf[arow];
            f16x8 a1 = *(const f16x8*)&xf[arow + 32];
            const int m0 = mt*16 + ((lane >> 4) << 2);
            const int r  = (m0 * 293) >> 13;        // m0/28
            const int u0 = m0 - 28*r;
            #pragma unroll
            for (int nt = 0; nt < 4; ++nt) {
                f32x4 d = f32x4{0.f, 0.f, 0.f, 0.f};
                d = __builtin_amdgcn_mfma_f32_16x16x32_f16(a0, wfr[nt][0], d, 0, 0, 0);
                d = __builtin_amdgcn_mfma_f32_16x16x32_f16(a1, wfr[nt][1], d, 0, 0, 0);
                const int cc = nt*16 + (lane & 15);
                *(uint2*)&xw[(r*64 + cc)*40 + u0] =
                    make_uint2(pk2h(d[0], d[1]), pk2h(d[2], d[3]));
            }
        }
        __syncthreads();

        // ---- phase 2: acc += xw @ An_i^T ----
        #pragma unroll
        for (int j = 0; j < 4; ++j) {
            const int mt2 = w + 4*j;
            f16x8 a = *(const f16x8*)&xw[(mt2*16 + (lane & 15))*40 + ((lane >> 4) << 3)];
            acc[j][0] = __builtin_amdgcn_mfma_f32_16x16x32_f16(a, anfr[i][0], acc[j][0], 0, 0, 0);
            acc[j][1] = __builtin_amdgcn_mfma_f32_16x16x32_f16(a, anfr[i][1], acc[j][1], 0, 0, 0);
        }
        __syncthreads();
    }

    // ---- epilogue: bias, BN1 partials, bf16 store ----
    float ssum[4] = {0.f, 0.f, 0.f, 0.f}, ssq[4] = {0.f, 0.f, 0.f, 0.f};
    const int vb = lane & 15;
    #pragma unroll
    for (int j = 0; j < 4; ++j) {
        #pragma unroll
        for (int nt = 0; nt < 2; ++nt) {
            const int v = nt*16 + vb;
            if (v < 25) {
                float o0 = acc[j][nt][0] + bs[0];
                float o1 = acc[j][nt][1] + bs[1];
                float o2 = acc[j][nt][2] + bs[2];
                float o3 = acc[j][nt][3] + bs[3];
                ssum[0] += o0; ssq[0] += o0*o0;
                ssum[1] += o1; ssq[1] += o1*o1;
                ssum[2] += o2; ssq[2] += o2*o2;
                ssum[3] += o3; ssq[3] += o3*o3;
                ushort4 pk;
                pk.x = f2b(o0); pk.y = f2b(o1); pk.z = f2b(o2); pk.w = f2b(o3);
                *(ushort4*)&out1[(size_t)(r0 + j)*STR + v*64 + c0] = pk;
            }
        }
    }
    #pragma unroll
    for (int t = 0; t < 4; ++t) {
        #pragma unroll
        for (int off = 1; off < 16; off <<= 1) {
            ssum[t] += __shfl_xor(ssum[t], off);
            ssq[t]  += __shfl_xor(ssq[t],  off);
        }
    }
    if ((lane & 15) == 0) {
        #pragma unroll
        for (int t = 0; t < 4; ++t) {
            p1[(size_t)blockIdx.x*128 + c0 + t]      = ssum[t];
            p1[(size_t)blockIdx.x*128 + 64 + c0 + t] = ssq[t];
        }
    }
}

// ---------------------------------------------------------------------------
// K3/K5: finalize BN stats -> scale/shift per channel (1024 threads)
// ---------------------------------------------------------------------------
template<bool F32>
__global__ void k_bnstats(const int* __restrict__ flag,
                          const float* __restrict__ part, int nblk,
                          const void* gamma, const void* beta,
                          float* __restrict__ scale, float* __restrict__ shift)
{
    if (flag[0] != (F32 ? 1 : 0)) return;
    __shared__ float redL[2048];
    const int tid = threadIdx.x, c = tid & 63, q = tid >> 6;   // q < 16
    float s = 0.0f, ss = 0.0f;
    for (int p = q; p < nblk; p += 16) { s += part[p*128 + c]; ss += part[p*128 + 64 + c]; }
    redL[q*64 + c] = s; redL[1024 + q*64 + c] = ss;
    __syncthreads();
    for (int h = 8; h > 0; h >>= 1) {
        if (q < h) {
            redL[q*64 + c]        += redL[(q+h)*64 + c];
            redL[1024 + q*64 + c] += redL[1024 + (q+h)*64 + c];
        }
        __syncthreads();
    }
    if (tid < 64) {
        const float S  = redL[tid];
        const float SS = redL[1024 + tid];
        const float m   = S / NSTAT;
        const float var = SS / NSTAT - m*m;
        const float rstd = rsqrtf(var + EPS_);
        const float sc = ldv<F32>(gamma, tid) * rstd;
        scale[tid] = sc;
        shift[tid] = ldv<F32>(beta, tid) - m * sc;
    }
}

// ---------------------------------------------------------------------------
// K_halo: save boundary out1 rows (t%30 in {0..3, 26..29}) into ws so the
// in-place temporal pass can read cross-tile halos after neighbors overwrite.
// ---------------------------------------------------------------------------
template<bool F32>
__global__ __launch_bounds__(128) void k_halo(const int* __restrict__ flag,
                                              const u16* out1, u16* halo)
{
    if (flag[0] != (F32 ? 1 : 0)) return;
    const int STR = Geo<F32>::STR;
    const int id = blockIdx.x;            // 64*10*8 = 5120
    const int slot = id & 7, tile = (id >> 3) % 10, b = id / 80;
    const int t = tile * TTILE + (slot < 4 ? slot : slot + 22);
    const uint4* src = (const uint4*)&out1[((size_t)b*T_ + t) * STR];
    uint4* dst = (uint4*)&halo[(size_t)id * ROWE];
    for (int j = threadIdx.x; j < 200; j += 128) dst[j] = src[j];
}

template<bool F32>
__device__ __forceinline__ const u16* row_ptr(const u16* out1, const u16* halo,
                                              int b, int s, int t0)
{
    if (s >= t0 && s < t0 + TTILE)
        return &out1[((size_t)b*T_ + s) * Geo<F32>::STR];
    const int tile = s / TTILE, rem = s % TTILE;
    const int slot = rem < 4 ? rem : rem - 22;
    return &halo[(((size_t)b*10 + tile)*8 + slot) * ROWE];
}

// ---------------------------------------------------------------------------
// K3_temporal (fused, single pass): per block one b, tile of 30 t's.
//   sliding window: h = relu(bn1(out1)) staged bf16 in LDS ring; per-thread
//   f32 hacc registers hold the band sum (8 channels each, tid<200).
//   per t: hsum -> f16 A-fragments in LDS; z = hsum@Wt + bt via 16 MFMA;
//   BN2 partials accumulated; z (f16) written IN PLACE over out1 row t
//   (out1[t] was consumed 5 steps earlier; cross-tile rows come from halo).
// ---------------------------------------------------------------------------
template<bool F32>
__global__ __launch_bounds__(256, 3) void k3_temporal(
    const int* __restrict__ flag,
    u16* out1, const u16* __restrict__ halo,
    const u16* __restrict__ wtT, const void* bt,
    const float* __restrict__ sc1, const float* __restrict__ sh1,
    float* __restrict__ p2)
{
    if (flag[0] != (F32 ? 1 : 0)) return;
    const int STR = Geo<F32>::STR;

    __shared__ u16   ring[10*1600];     // h rows (bf16), 32 KB
    __shared__ f16   hsumH[32*72];      // hsum f16, A-operand layout, 4.6 KB
    __shared__ u16   zL[1600];          // z row (f16), 3.2 KB
    __shared__ float redL[256];

    const int tid = threadIdx.x, lane = tid & 63, w = tid >> 6;
    const int b = blockIdx.y, t0 = blockIdx.x * TTILE;
    const bool act = (tid < 200);

    // zero hsumH pad rows 25..31 (read by mt=1 lanes, results discarded)
    for (int i = tid; i < 252; i += 256) ((u32*)&hsumH[25*72])[i] = 0u;

    // per-thread channel slice: jj = tid*8 + e  (v = tid/8, k0 = (tid*8)&63)
    float hacc[8];
    #pragma unroll
    for (int e = 0; e < 8; ++e) hacc[e] = 0.0f;
    const int c0u = (tid*8) & 63;
    const int vrow = tid >> 3;
    float S1[8], H1[8];
    #pragma unroll
    for (int e = 0; e < 8; ++e) { S1[e] = sc1[c0u+e]; H1[e] = sh1[c0u+e]; }

    // Wt B-fragments for this wave's nt pair
    const int ntp = w >> 1, mt = w & 1;
    f16x8 wfr[2][2];
    #pragma unroll
    for (int ntl = 0; ntl < 2; ++ntl)
        #pragma unroll
        for (int ks = 0; ks < 2; ++ks)
            wfr[ntl][ks] = *(const f16x8*)&wtT[
                ((ntp*2+ntl)*16 + (lane & 15))*72 + ks*32 + ((lane >> 4) << 3)];
    float btv[2];
    #pragma unroll
    for (int ntl = 0; ntl < 2; ++ntl)
        btv[ntl] = ldv<F32>(bt, (ntp*2+ntl)*16 + (lane & 15));

    // ---- initial window [t0-4, t0+4] ----
    {
        int slo = t0 - 4; if (slo < 0) slo = 0;
        for (int s = slo; s <= t0 + 4; ++s) {
            const u16* xr = row_ptr<F32>(out1, halo, b, s, t0);
            if (act) {
                uint4 xv = *(const uint4*)&xr[tid*8];
                const u16* xs = (const u16*)&xv;
                u16 hb[8];
                #pragma unroll
                for (int e = 0; e < 8; ++e) {
                    float hv = fmaf(b2f(xs[e]), S1[e], H1[e]);
                    hv = hv > 0.0f ? hv : 0.0f;
                    hb[e] = f2b(hv);
                    hacc[e] += b2f(hb[e]);
                }
                *(uint4*)&ring[(s%10)*1600 + tid*8] = *(uint4*)hb;
            }
        }
        if (act) {
            u16 hs[8];
            #pragma unroll
            for (int e = 0; e < 8; ++e) hs[e] = h2u(hacc[e]);
            *(uint4*)&hsumH[vrow*72 + c0u] = *(uint4*)hs;
        }
    }
    __syncthreads();

    float zs[2] = {0.f, 0.f}, zq[2] = {0.f, 0.f};

    for (int t = t0; t < t0 + TTILE; ++t) {
        // ---- phase M: z = hsum @ Wt + bt (MFMA), stats, stage z into zL ----
        {
            const int arow = (mt*16 + (lane & 15))*72 + ((lane >> 4) << 3);
            f16x8 a0 = *(const f16x8*)&hsumH[arow];
            f16x8 a1 = *(const f16x8*)&hsumH[arow + 32];
            #pragma unroll
            for (int ntl = 0; ntl < 2; ++ntl) {
                f32x4 d = f32x4{btv[ntl], btv[ntl], btv[ntl], btv[ntl]};
                d = __builtin_amdgcn_mfma_f32_16x16x32_f16(a0, wfr[ntl][0], d, 0, 0, 0);
                d = __builtin_amdgcn_mfma_f32_16x16x32_f16(a1, wfr[ntl][1], d, 0, 0, 0);
                const int cc = (ntp*2+ntl)*16 + (lane & 15);
                #pragma unroll
                for (int j = 0; j < 4; ++j) {
                    const int v = mt*16 + ((lane >> 4) << 2) + j;
                    if (v < 25) {
                        zs[ntl] += d[j]; zq[ntl] += d[j]*d[j];
                        zL[v*64 + cc] = h2u(d[j]);
                    }
                }
            }
        }
        __syncthreads();

        // ---- phase U: write z row t; advance window to t+1 ----
        if (tid < 200)
            *(uint4*)&out1[((size_t)b*T_ + t)*STR + tid*8] = ((const uint4*)zL)[tid];

        if (t + 1 < t0 + TTILE) {
            const int snew = t + 5, sold = t - 4;
            if (act) {
                if (snew < T_) {
                    const u16* xr = row_ptr<F32>(out1, halo, b, snew, t0);
                    uint4 xv = *(const uint4*)&xr[tid*8];
                    const u16* xs = (const u16*)&xv;
                    u16 hb[8];
                    #pragma unroll
                    for (int e = 0; e < 8; ++e) {
                        float hv = fmaf(b2f(xs[e]), S1[e], H1[e]);
                        hv = hv > 0.0f ? hv : 0.0f;
                        hb[e] = f2b(hv);
                        hacc[e] += b2f(hb[e]);
                    }
                    *(uint4*)&ring[(snew%10)*1600 + tid*8] = *(uint4*)hb;
                }
                if (sold >= 0) {
                    uint4 ov = *(const uint4*)&ring[(sold%10)*1600 + tid*8];
                    const u16* os = (const u16*)&ov;
                    #pragma unroll
                    for (int e = 0; e < 8; ++e) hacc[e] -= b2f(os[e]);
                }
                u16 hs[8];
                #pragma unroll
                for (int e = 0; e < 8; ++e) hs[e] = h2u(hacc[e]);
                *(uint4*)&hsumH[vrow*72 + c0u] = *(uint4*)hs;
            }
        }
        __syncthreads();
    }

    // ---- BN2 partials: reduce over lane>>4 groups, then mt waves via LDS ----
    #pragma unroll
    for (int ntl = 0; ntl < 2; ++ntl) {
        #pragma unroll
        for (int off = 16; off < 64; off <<= 1) {
            zs[ntl] += __shfl_xor(zs[ntl], off);
            zq[ntl] += __shfl_xor(zq[ntl], off);
        }
    }
    if (lane < 16) {
        redL[w*32 + lane]        = zs[0];
        redL[w*32 + 16 + lane]   = zs[1];
        redL[128 + w*32 + lane]      = zq[0];
        redL[128 + w*32 + 16 + lane] = zq[1];
    }
    __syncthreads();
    if (tid < 64) {
        const int c = tid;
        const int ntg = c >> 4, pr = ntg >> 1, ntl = ntg & 1, l = c & 15;
        const int w0 = pr*2, w1 = pr*2 + 1;
        float s = redL[w0*32 + ntl*16 + l] + redL[w1*32 + ntl*16 + l];
        float q = redL[128 + w0*32 + ntl*16 + l] + redL[128 + w1*32 + ntl*16 + l];
        const int blk = blockIdx.y * (T_/TTILE) + blockIdx.x;
        p2[(size_t)blk*128 + c]      = s;
        p2[(size_t)blk*128 + 64 + c] = q;
    }
}

// ---------------------------------------------------------------------------
// K4_final: elementwise out = relu(z*sc2 + sh2), z read f16 from staging,
// written in place (bf16 same bytes; f32 expands over the full row -> read
// row to regs, sync, then store).
// ---------------------------------------------------------------------------
template<bool F32>
__global__ __launch_bounds__(256) void k4_final(
    const int* __restrict__ flag,
    const float* __restrict__ sc2, const float* __restrict__ sh2,
    void* outp)
{
    if (flag[0] != (F32 ? 1 : 0)) return;
    const int STR = Geo<F32>::STR;
    const int tid = threadIdx.x;
    const int c0u = (tid*8) & 63;
    float S2[8], H2[8];
    #pragma unroll
    for (int e = 0; e < 8; ++e) { S2[e] = sc2[c0u+e]; H2[e] = sh2[c0u+e]; }
    const int r0 = blockIdx.x * 10;
    u16* z = (u16*)outp;

    for (int r = 0; r < 10; ++r) {
        const int row = r0 + r;
        uint4 zv;
        if (tid < 200) zv = *(const uint4*)&z[(size_t)row*STR + tid*8];
        __syncthreads();
        if (tid < 200) {
            const u16* zp = (const u16*)&zv;
            float o[8];
            #pragma unroll
            for (int e = 0; e < 8; ++e) {
                float oo = fmaf(u2h(zp[e]), S2[e], H2[e]);
                o[e] = oo > 0.0f ? oo : 0.0f;
            }
            if (F32) {
                float* dst = (float*)outp + (size_t)row*ROWE + tid*8;
                *(float4*)dst     = float4{o[0], o[1], o[2], o[3]};
                *(float4*)(dst+4) = float4{o[4], o[5], o[6], o[7]};
            } else {
                u16 ob[8];
                #pragma unroll
                for (int e = 0; e < 8; ++e) ob[e] = f2b(o[e]);
                *(uint4*)&((u16*)outp)[(size_t)row*ROWE + tid*8] = *(uint4*)ob;
            }
        }
    }
}

// ---------------------------------------------------------------------------
extern "C" void kernel_launch(void* const* d_in, const int* in_sizes, int n_in,
                              void* d_out, int out_size, void* d_ws, size_t ws_size,
                              hipStream_t stream)
{
    const void* x     = d_in[0];
    const void* A     = d_in[1];
    const void* E     = d_in[2];
    const void* W1    = d_in[3];
    const void* b1    = d_in[4];
    const void* W2    = d_in[5];
    const void* b2    = d_in[6];
    const void* W3    = d_in[7];
    const void* b3    = d_in[8];
    const void* Wt    = d_in[9];
    const void* bt    = d_in[10];
    const void* gamma = d_in[11];
    const void* beta  = d_in[12];

    u16* out1 = (u16*)d_out;          // stage-1 staging lives in d_out

    // ws layout — front of d_ws; total ≈ 19.2 MB.
    int*   flag = (int*)d_ws;
    float* wsf  = (float*)d_ws;
    float* bsum = wsf + 4;
    float* sc1  = bsum + 64;
    float* sh1  = sc1 + 64;
    float* sc2  = sh1 + 64;
    float* sh2  = sc2 + 64;
    float* p1   = sh2 + 64;                       // K2GRID*128
    float* p2   = p1 + (size_t)K2GRID*128;        // 640*128
    u16*  halo  = (u16*)(p2 + 640*128);           // 5120*1600 u16 = 16.4 MB
    u16*  wcatT = halo + (size_t)5120*1600;       // 13824 f16
    u16*  anf   = wcatT + 13824;                  // 3072 f16
    u16*  wtT   = anf + 3072;                     // 4608 f16

    hipLaunchKernelGGL(k0_detect, dim3(1), dim3(256), 0, stream, W1, flag);

    hipLaunchKernelGGL(k1_prep<false>, dim3(1), dim3(256), 0, stream,
                       flag, A, E, W1, W2, W3, Wt, b1, b2, b3, anf, wcatT, wtT, bsum);
    hipLaunchKernelGGL(k1_prep<true>, dim3(1), dim3(256), 0, stream,
                       flag, A, E, W1, W2, W3, Wt, b1, b2, b3, anf, wcatT, wtT, bsum);

    hipLaunchKernelGGL(k2_mfma<false>, dim3(K2GRID), dim3(256), 0, stream,
                       flag, x, wcatT, anf, bsum, out1, p1);
    hipLaunchKernelGGL(k2_mfma<true>, dim3(K2GRID), dim3(256), 0, stream,
                       flag, x, wcatT, anf, bsum, out1, p1);

    hipLaunchKernelGGL(k_bnstats<false>, dim3(1), dim3(1024), 0, stream,
                       flag, p1, K2GRID, gamma, beta, sc1, sh1);
    hipLaunchKernelGGL(k_bnstats<true>, dim3(1), dim3(1024), 0, stream,
                       flag, p1, K2GRID, gamma, beta, sc1, sh1);

    hipLaunchKernelGGL(k_halo<false>, dim3(5120), dim3(128), 0, stream,
                       flag, out1, halo);
    hipLaunchKernelGGL(k_halo<true>, dim3(5120), dim3(128), 0, stream,
                       flag, out1, halo);

    hipLaunchKernelGGL(k3_temporal<false>, dim3(10, 64), dim3(256), 0, stream,
                       flag, out1, halo, wtT, bt, sc1, sh1, p2);
    hipLaunchKernelGGL(k3_temporal<true>, dim3(10, 64), dim3(256), 0, stream,
                       flag, out1, halo, wtT, bt, sc1, sh1, p2);

    hipLaunchKernelGGL(k_bnstats<false>, dim3(1), dim3(1024), 0, stream,
                       flag, p2, 640, gamma, beta, sc2, sh2);
    hipLaunchKernelGGL(k_bnstats<true>, dim3(1), dim3(1024), 0, stream,
                       flag, p2, 640, gamma, beta, sc2, sh2);

    hipLaunchKernelGGL(k4_final<false>, dim3(1920), dim3(256), 0, stream,
                       flag, sc2, sh2, d_out);
    hipLaunchKernelGGL(k4_final<true>, dim3(1920), dim3(256), 0, stream,
                       flag, sc2, sh2, d_out);
}

// Round 3
// 439.818 us; speedup vs baseline: 4.5268x; 1.1183x over previous
//
#include <hip/hip_runtime.h>

typedef unsigned short u16;
typedef unsigned int   u32;
typedef _Float16       f16;
typedef _Float16 f16x8 __attribute__((ext_vector_type(8)));
typedef float    f32x4 __attribute__((ext_vector_type(4)));

#define B_  64
#define T_  300
#define V_  25
#define C_  64
#define ROWS (B_*T_)          // 19200
#define ROWE (V_*C_)          // 1600
#define NSTAT 480000.0f       // B*T*V
#define EPS_ 1e-5f
#define TTILE 30              // temporal tile (10 tiles of 30)
#define K2BLK 1200            // k2 blocks (4 waves x 4 rows each)
#define NWID  4800            // k2 wave count (p1 rows)

__device__ __forceinline__ float b2f(u16 u) {
    union { u32 i; float f; } v; v.i = ((u32)u) << 16; return v.f;
}
__device__ __forceinline__ u16 f2b(float f) {  // round-to-nearest-even
    union { float f; u32 i; } v; v.f = f;
    u32 x = v.i;
    u32 r = x + 0x7fffu + ((x >> 16) & 1u);
    return (u16)(r >> 16);
}
__device__ __forceinline__ u32 pk2h(float a, float b) {   // pack 2 f32 -> 2 f16
    union { f16 h[2]; u32 u; } p;
    p.h[0] = (f16)a; p.h[1] = (f16)b;
    return p.u;
}
__device__ __forceinline__ u16 h2u(float v) {             // f32 -> f16 bits
    union { f16 h; u16 u; } p; p.h = (f16)v; return p.u;
}
__device__ __forceinline__ float u2h(u16 u) {             // f16 bits -> f32
    union { u16 u; f16 h; } p; p.u = u; return (float)p.h;
}

template<bool F32>
__device__ __forceinline__ float ldv(const void* p, size_t i) {
    if (F32) return ((const float*)p)[i];
    return b2f(((const u16*)p)[i]);
}

// staging row stride in u16 units (fp32 mode: staging row r sits in the
// low half of fp32 output row r's byte range -> in-place overwrite is safe).
template<bool F32> struct Geo { static const int STR = F32 ? 3200 : 1600; };

// ---------------------------------------------------------------------------
// K0: dtype detection (device-side ground truth; host fast-path uses in_sizes)
// ---------------------------------------------------------------------------
__global__ void k0_detect(const void* W1raw, int* flag)
{
    __shared__ float red[256];
    const u16* p = (const u16*)W1raw;
    float mx = 0.0f;
    for (int i = threadIdx.x; i < 4096; i += 256) {
        float v = fabsf(b2f(p[i]));
        if (v == v) mx = fmaxf(mx, v);
    }
    red[threadIdx.x] = mx;
    __syncthreads();
    for (int s = 128; s > 0; s >>= 1) {
        if (threadIdx.x < s) red[threadIdx.x] = fmaxf(red[threadIdx.x], red[threadIdx.x + s]);
        __syncthreads();
    }
    if (threadIdx.x == 0) flag[0] = (red[0] > 1e10f) ? 1 : 0;
}

// ---------------------------------------------------------------------------
// K1: prep tables.
//   anf  : An^T fragments (k2 phase-2 B-operand), 3072 f16.
//   wcatT: wcatT[i][c][k(pad 72)] = W_i[k][c], 13824 f16 (k2 phase-1 B).
//   wtT  : wtT[c][k(pad 72)] = Wt[k][c], 4608 f16 (k3 B-operand).
//   bsum : b1+b2+b3 (folded into BN1 mean, NOT added in k2).
// ---------------------------------------------------------------------------
template<bool F32>
__global__ void k1_prep(const int* __restrict__ flag,
                        const void* A, const void* E,
                        const void* W1, const void* W2, const void* W3,
                        const void* Wt,
                        const void* b1, const void* b2, const void* b3,
                        u16* __restrict__ anf, u16* __restrict__ wcatT,
                        u16* __restrict__ wtT, float* __restrict__ bsum)
{
    if (flag[0] != (F32 ? 1 : 0)) return;
    __shared__ float dinvL[75];
    const int tid = threadIdx.x;
    if (tid < 75) {
        int i = tid / 25, v = tid % 25;
        float d = 1.0f;                       // diagonal forced to 1
        for (int u = 0; u < 25; ++u)
            if (u != v) d += ldv<F32>(A, (i*25+v)*25+u) * ldv<F32>(E, (i*25+v)*25+u);
        dinvL[tid] = (d > 0.0f) ? rsqrtf(d) : 0.0f;
    }
    __syncthreads();
    // An^T fragments: B[k=u][n=v] layout per lane
    for (int idx = tid; idx < 3072; idx += 256) {
        int fr = idx >> 9, lane = (idx >> 3) & 63, j = idx & 7;
        int i = fr >> 1, nt = fr & 1;
        int v = nt*16 + (lane & 15);
        int u = ((lane >> 4) << 3) + j;
        float val = 0.0f;
        if (v < 25 && u < 25) {
            float ad = (u == v) ? 1.0f
                     : ldv<F32>(A, (i*25+v)*25+u) * ldv<F32>(E, (i*25+v)*25+u);
            val = dinvL[i*25+v] * ad * dinvL[i*25+u];
        }
        anf[idx] = h2u(val);
    }
    // WcatT[i][c][k] = W_i[k][c], rows padded to 72 halfs
    for (int idx = tid; idx < 13824; idx += 256) {
        int i = idx / 4608;
        int rem = idx - i*4608;
        int c = rem / 72, k = rem - (rem/72)*72;
        float val = 0.0f;
        if (k < 64) {
            const void* W = (i == 0) ? W1 : ((i == 1) ? W2 : W3);
            val = ldv<F32>(W, k*64 + c);
        }
        wcatT[idx] = h2u(val);
    }
    // WtT[c][k] = Wt[k][c], rows padded to 72 halfs
    for (int idx = tid; idx < 4608; idx += 256) {
        int c = idx / 72, k = idx - (idx/72)*72;
        float val = (k < 64) ? ldv<F32>(Wt, k*64 + c) : 0.0f;
        wtT[idx] = h2u(val);
    }
    if (tid < 64) bsum[tid] = ldv<F32>(b1, tid) + ldv<F32>(b2, tid) + ldv<F32>(b3, tid);
}

// ---------------------------------------------------------------------------
// K2 (MFMA, barrier-free): each wave owns rows independently; per-wave LDS.
//   xf: [u(32 rows)][64 halfs], 16B-granule XOR-swizzled (g ^= u&7)
//   xw: [c(64 rows)][64 halfs phys / 32 logical], granule XOR (g ^= c&7)
//   phase1 per branch: xw[c][u] = (x @ W_i)^T via 16 mfma 16x16x32
//   phase2 per branch: acc[c][v] += xw @ An_i^T via 8 mfma
//   epilogue: out1 (no bias; BN absorbs it), halo rows, BN1 partials.
// ---------------------------------------------------------------------------
template<bool F32>
__global__ __launch_bounds__(256, 3) void k2_mfma(
    const int* __restrict__ flag, const void* x,
    const u16* __restrict__ wcatT, const u16* __restrict__ anf,
    u16* __restrict__ out1, u16* __restrict__ halo, float* __restrict__ p1)
{
    if (flag[0] != (F32 ? 1 : 0)) return;
    const int STR = Geo<F32>::STR;

    __shared__ f16 xfS[4][32*64];   // 16 KB
    __shared__ u16 xwS[4][64*64];   // 32 KB

    const int tid = threadIdx.x, lane = tid & 63, w = tid >> 6;
    const int lo = lane & 15, hi = lane >> 4;
    f16* xf = xfS[w];
    u16* xw = xwS[w];

    // zero xf pad rows u=25..31 (once; never overwritten by staging)
    for (int q = lane; q < 224; q += 64) ((u32*)xf)[800 + q] = 0u;

    const int wid = blockIdx.x*4 + w;      // 0..4799

    float ss[16], sq[16];
    #pragma unroll
    for (int i = 0; i < 16; ++i) { ss[i] = 0.0f; sq[i] = 0.0f; }

    #pragma unroll 1
    for (int rr = 0; rr < 4; ++rr) {
        const int row = wid*4 + rr;

        // ---- stage x row as f16 into xf (swizzled) ----
        for (int q = lane; q < 200; q += 64) {
            const int u = q >> 3, g = q & 7;
            float v0,v1,v2,v3,v4,v5,v6,v7;
            if (F32) {
                float4 a4 = ((const float4*)x)[(size_t)row*400 + q*2];
                float4 b4 = ((const float4*)x)[(size_t)row*400 + q*2 + 1];
                v0=a4.x; v1=a4.y; v2=a4.z; v3=a4.w;
                v4=b4.x; v5=b4.y; v6=b4.z; v7=b4.w;
            } else {
                union { uint4 u4; u16 s[8]; } t4;
                t4.u4 = ((const uint4*)x)[(size_t)row*200 + q];
                v0=b2f(t4.s[0]); v1=b2f(t4.s[1]); v2=b2f(t4.s[2]); v3=b2f(t4.s[3]);
                v4=b2f(t4.s[4]); v5=b2f(t4.s[5]); v6=b2f(t4.s[6]); v7=b2f(t4.s[7]);
            }
            uint4 st = make_uint4(pk2h(v0,v1), pk2h(v2,v3), pk2h(v4,v5), pk2h(v6,v7));
            *(uint4*)&xf[u*64 + ((g ^ (u & 7)) << 3)] = st;
        }

        f32x4 acc[4][2];
        #pragma unroll
        for (int m = 0; m < 4; ++m) {
            acc[m][0] = f32x4{0.f,0.f,0.f,0.f};
            acc[m][1] = f32x4{0.f,0.f,0.f,0.f};
        }

        #pragma unroll 1
        for (int i = 0; i < 3; ++i) {
            // W fragments (global, L1/L2-hot)
            f16x8 wfr[4][2];
            #pragma unroll
            for (int nt = 0; nt < 4; ++nt)
                #pragma unroll
                for (int ks = 0; ks < 2; ++ks)
                    wfr[nt][ks] = *(const f16x8*)&wcatT[
                        (size_t)(i*64 + nt*16 + lo)*72 + ks*32 + (hi << 3)];
            // An^T fragments for this branch
            f16x8 an0 = *(const f16x8*)&anf[((i*2 + 0)*64 + lane)*8];
            f16x8 an1 = *(const f16x8*)&anf[((i*2 + 1)*64 + lane)*8];

            // ---- phase 1: xw[c][u] = x @ W_i ----
            #pragma unroll
            for (int mt = 0; mt < 2; ++mt) {
                const int mrow = mt*16 + lo;
                f16x8 a0 = *(const f16x8*)&xf[mrow*64 + ((hi ^ (lo & 7)) << 3)];
                f16x8 a1 = *(const f16x8*)&xf[mrow*64 + (((4|hi) ^ (lo & 7)) << 3)];
                const int gu  = mt*2 + (hi >> 1);
                const int off = (hi & 1)*4;
                #pragma unroll
                for (int nt = 0; nt < 4; ++nt) {
                    f32x4 d = f32x4{0.f,0.f,0.f,0.f};
                    d = __builtin_amdgcn_mfma_f32_16x16x32_f16(a0, wfr[nt][0], d, 0, 0, 0);
                    d = __builtin_amdgcn_mfma_f32_16x16x32_f16(a1, wfr[nt][1], d, 0, 0, 0);
                    const int c = nt*16 + lo;
                    *(uint2*)&xw[c*64 + ((gu ^ (lo & 7)) << 3) + off] =
                        make_uint2(pk2h(d[0], d[1]), pk2h(d[2], d[3]));
                }
            }

            // ---- phase 2: acc[c][v] += xw @ An_i^T ----
            #pragma unroll
            for (int mt2 = 0; mt2 < 4; ++mt2) {
                f16x8 a = *(const f16x8*)&xw[(mt2*16 + lo)*64 + ((hi ^ (lo & 7)) << 3)];
                acc[mt2][0] = __builtin_amdgcn_mfma_f32_16x16x32_f16(a, an0, acc[mt2][0], 0, 0, 0);
                acc[mt2][1] = __builtin_amdgcn_mfma_f32_16x16x32_f16(a, an1, acc[mt2][1], 0, 0, 0);
            }
        }

        // ---- epilogue: out1 store (no bias), halo rows, BN1 partials ----
        const int b = row / T_;
        const int t = row - b*T_;
        const int tm = t % TTILE;
        const bool hbd = (tm < 4) || (tm >= TTILE - 4);
        u16* hrow = nullptr;
        if (hbd) {
            const int slot = tm < 4 ? tm : tm - 22;
            hrow = halo + (((size_t)b*10 + t/TTILE)*8 + slot)*ROWE;
        }
        u16* orow = out1 + (size_t)row*STR;
        #pragma unroll
        for (int mt2 = 0; mt2 < 4; ++mt2) {
            const int c0 = mt2*16 + hi*4;
            #pragma unroll
            for (int nt2 = 0; nt2 < 2; ++nt2) {
                const int v = nt2*16 + lo;
                const float o0 = acc[mt2][nt2][0];
                const float o1 = acc[mt2][nt2][1];
                const float o2 = acc[mt2][nt2][2];
                const float o3 = acc[mt2][nt2][3];
                ss[mt2*4+0] += o0; sq[mt2*4+0] += o0*o0;
                ss[mt2*4+1] += o1; sq[mt2*4+1] += o1*o1;
                ss[mt2*4+2] += o2; sq[mt2*4+2] += o2*o2;
                ss[mt2*4+3] += o3; sq[mt2*4+3] += o3*o3;
                if (v < 25) {
                    ushort4 pk;
                    pk.x = f2b(o0); pk.y = f2b(o1); pk.z = f2b(o2); pk.w = f2b(o3);
                    *(ushort4*)&orow[v*64 + c0] = pk;
                    if (hbd) *(ushort4*)&hrow[v*64 + c0] = pk;
                }
            }
        }
    }

    // ---- BN1 partials: reduce over the 16 lanes sharing each channel ----
    #pragma unroll
    for (int si = 0; si < 16; ++si) {
        #pragma unroll
        for (int off = 1; off < 16; off <<= 1) {
            ss[si] += __shfl_xor(ss[si], off);
            sq[si] += __shfl_xor(sq[si], off);
        }
    }
    if (lo == 0) {
        #pragma unroll
        for (int si = 0; si < 16; ++si) {
            const int c = (si >> 2)*16 + hi*4 + (si & 3);
            p1[(size_t)wid*128 + c]      = ss[si];
            p1[(size_t)wid*128 + 64 + c] = sq[si];
        }
    }
}

// ---------------------------------------------------------------------------
// K_reduce: parallel partial-sum reduce part[n][128] -> q[64][128]. dtype-free.
// ---------------------------------------------------------------------------
__global__ __launch_bounds__(128) void k_reduce(const float* __restrict__ in,
                                                int n, float* __restrict__ outq)
{
    const int t = threadIdx.x;
    float s = 0.0f;
    for (int r = blockIdx.x; r < n; r += 64) s += in[(size_t)r*128 + t];
    outq[(size_t)blockIdx.x*128 + t] = s;
}

// ---------------------------------------------------------------------------
// K_bnstats: finalize from q[64][128]. useb: add mb[c] to the mean (bias fold).
// ---------------------------------------------------------------------------
template<bool F32>
__global__ void k_bnstats(const int* __restrict__ flag,
                          const float* __restrict__ q,
                          const void* gamma, const void* beta,
                          const float* __restrict__ mb, int useb,
                          float* __restrict__ scale, float* __restrict__ shift)
{
    if (flag[0] != (F32 ? 1 : 0)) return;
    __shared__ float redL[512];
    const int tid = threadIdx.x, c = tid & 63, g = tid >> 6;   // g < 4
    float s = 0.0f, ssq = 0.0f;
    for (int r = g; r < 64; r += 4) { s += q[r*128 + c]; ssq += q[r*128 + 64 + c]; }
    redL[g*64 + c] = s; redL[256 + g*64 + c] = ssq;
    __syncthreads();
    if (tid < 64) {
        const float S  = redL[tid] + redL[64+tid] + redL[128+tid] + redL[192+tid];
        const float SS = redL[256+tid] + redL[320+tid] + redL[384+tid] + redL[448+tid];
        const float my  = S / NSTAT;                 // mean of y (bias-free)
        const float var = SS / NSTAT - my*my;        // var(y+b) == var(y)
        const float m   = my + (useb ? mb[tid] : 0.0f);
        const float rstd = rsqrtf(var + EPS_);
        const float sc = ldv<F32>(gamma, tid) * rstd;
        scale[tid] = sc;
        shift[tid] = ldv<F32>(beta, tid) - m * sc;
    }
}

template<bool F32>
__device__ __forceinline__ const u16* row_ptr(const u16* out1, const u16* halo,
                                              int b, int s, int t0)
{
    if (s >= t0 && s < t0 + TTILE)
        return &out1[((size_t)b*T_ + s) * Geo<F32>::STR];
    const int tile = s / TTILE, rem = s % TTILE;
    const int slot = rem < 4 ? rem : rem - 22;
    return &halo[(((size_t)b*10 + tile)*8 + slot) * ROWE];
}

// ---------------------------------------------------------------------------
// K3_temporal (fused, single pass): per block one b, tile of 30 t's.
// ---------------------------------------------------------------------------
template<bool F32>
__global__ __launch_bounds__(256, 3) void k3_temporal(
    const int* __restrict__ flag,
    u16* out1, const u16* __restrict__ halo,
    const u16* __restrict__ wtT, const void* bt,
    const float* __restrict__ sc1, const float* __restrict__ sh1,
    float* __restrict__ p2)
{
    if (flag[0] != (F32 ? 1 : 0)) return;
    const int STR = Geo<F32>::STR;

    __shared__ u16   ring[10*1600];     // h rows (bf16), 32 KB
    __shared__ f16   hsumH[32*72];      // hsum f16, A-operand layout, 4.6 KB
    __shared__ u16   zL[1600];          // z row (f16), 3.2 KB
    __shared__ float redL[256];

    const int tid = threadIdx.x, lane = tid & 63, w = tid >> 6;
    const int b = blockIdx.y, t0 = blockIdx.x * TTILE;
    const bool act = (tid < 200);

    // zero hsumH pad rows 25..31
    for (int i = tid; i < 252; i += 256) ((u32*)&hsumH[25*72])[i] = 0u;

    float hacc[8];
    #pragma unroll
    for (int e = 0; e < 8; ++e) hacc[e] = 0.0f;
    const int c0u = (tid*8) & 63;
    const int vrow = tid >> 3;
    float S1[8], H1[8];
    #pragma unroll
    for (int e = 0; e < 8; ++e) { S1[e] = sc1[c0u+e]; H1[e] = sh1[c0u+e]; }

    const int ntp = w >> 1, mt = w & 1;
    f16x8 wfr[2][2];
    #pragma unroll
    for (int ntl = 0; ntl < 2; ++ntl)
        #pragma unroll
        for (int ks = 0; ks < 2; ++ks)
            wfr[ntl][ks] = *(const f16x8*)&wtT[
                ((ntp*2+ntl)*16 + (lane & 15))*72 + ks*32 + ((lane >> 4) << 3)];
    float btv[2];
    #pragma unroll
    for (int ntl = 0; ntl < 2; ++ntl)
        btv[ntl] = ldv<F32>(bt, (ntp*2+ntl)*16 + (lane & 15));

    {   // initial window [t0-4, t0+4]
        int slo = t0 - 4; if (slo < 0) slo = 0;
        for (int s = slo; s <= t0 + 4; ++s) {
            const u16* xr = row_ptr<F32>(out1, halo, b, s, t0);
            if (act) {
                uint4 xv = *(const uint4*)&xr[tid*8];
                const u16* xs = (const u16*)&xv;
                u16 hb[8];
                #pragma unroll
                for (int e = 0; e < 8; ++e) {
                    float hv = fmaf(b2f(xs[e]), S1[e], H1[e]);
                    hv = hv > 0.0f ? hv : 0.0f;
                    hb[e] = f2b(hv);
                    hacc[e] += b2f(hb[e]);
                }
                *(uint4*)&ring[(s%10)*1600 + tid*8] = *(uint4*)hb;
            }
        }
        if (act) {
            u16 hs[8];
            #pragma unroll
            for (int e = 0; e < 8; ++e) hs[e] = h2u(hacc[e]);
            *(uint4*)&hsumH[vrow*72 + c0u] = *(uint4*)hs;
        }
    }
    __syncthreads();

    float zs[2] = {0.f, 0.f}, zq[2] = {0.f, 0.f};

    for (int t = t0; t < t0 + TTILE; ++t) {
        {   // phase M: z = hsum @ Wt + bt (MFMA), stats, stage z
            const int arow = (mt*16 + (lane & 15))*72 + ((lane >> 4) << 3);
            f16x8 a0 = *(const f16x8*)&hsumH[arow];
            f16x8 a1 = *(const f16x8*)&hsumH[arow + 32];
            #pragma unroll
            for (int ntl = 0; ntl < 2; ++ntl) {
                f32x4 d = f32x4{btv[ntl], btv[ntl], btv[ntl], btv[ntl]};
                d = __builtin_amdgcn_mfma_f32_16x16x32_f16(a0, wfr[ntl][0], d, 0, 0, 0);
                d = __builtin_amdgcn_mfma_f32_16x16x32_f16(a1, wfr[ntl][1], d, 0, 0, 0);
                const int cc = (ntp*2+ntl)*16 + (lane & 15);
                #pragma unroll
                for (int j = 0; j < 4; ++j) {
                    const int v = mt*16 + ((lane >> 4) << 2) + j;
                    if (v < 25) {
                        zs[ntl] += d[j]; zq[ntl] += d[j]*d[j];
                        zL[v*64 + cc] = h2u(d[j]);
                    }
                }
            }
        }
        __syncthreads();

        if (tid < 200)
            *(uint4*)&out1[((size_t)b*T_ + t)*STR + tid*8] = ((const uint4*)zL)[tid];

        if (t + 1 < t0 + TTILE) {
            const int snew = t + 5, sold = t - 4;
            if (act) {
                if (snew < T_) {
                    const u16* xr = row_ptr<F32>(out1, halo, b, snew, t0);
                    uint4 xv = *(const uint4*)&xr[tid*8];
                    const u16* xs = (const u16*)&xv;
                    u16 hb[8];
                    #pragma unroll
                    for (int e = 0; e < 8; ++e) {
                        float hv = fmaf(b2f(xs[e]), S1[e], H1[e]);
                        hv = hv > 0.0f ? hv : 0.0f;
                        hb[e] = f2b(hv);
                        hacc[e] += b2f(hb[e]);
                    }
                    *(uint4*)&ring[(snew%10)*1600 + tid*8] = *(uint4*)hb;
                }
                if (sold >= 0) {
                    uint4 ov = *(const uint4*)&ring[(sold%10)*1600 + tid*8];
                    const u16* os = (const u16*)&ov;
                    #pragma unroll
                    for (int e = 0; e < 8; ++e) hacc[e] -= b2f(os[e]);
                }
                u16 hs[8];
                #pragma unroll
                for (int e = 0; e < 8; ++e) hs[e] = h2u(hacc[e]);
                *(uint4*)&hsumH[vrow*72 + c0u] = *(uint4*)hs;
            }
        }
        __syncthreads();
    }

    #pragma unroll
    for (int ntl = 0; ntl < 2; ++ntl) {
        #pragma unroll
        for (int off = 16; off < 64; off <<= 1) {
            zs[ntl] += __shfl_xor(zs[ntl], off);
            zq[ntl] += __shfl_xor(zq[ntl], off);
        }
    }
    if (lane < 16) {
        redL[w*32 + lane]            = zs[0];
        redL[w*32 + 16 + lane]       = zs[1];
        redL[128 + w*32 + lane]      = zq[0];
        redL[128 + w*32 + 16 + lane] = zq[1];
    }
    __syncthreads();
    if (tid < 64) {
        const int c = tid;
        const int ntg = c >> 4, pr = ntg >> 1, ntl = ntg & 1, l = c & 15;
        const int w0 = pr*2, w1 = pr*2 + 1;
        float s = redL[w0*32 + ntl*16 + l] + redL[w1*32 + ntl*16 + l];
        float q = redL[128 + w0*32 + ntl*16 + l] + redL[128 + w1*32 + ntl*16 + l];
        const int blk = blockIdx.y * (T_/TTILE) + blockIdx.x;
        p2[(size_t)blk*128 + c]      = s;
        p2[(size_t)blk*128 + 64 + c] = q;
    }
}

// ---------------------------------------------------------------------------
// K4_final: out = relu(z*sc2 + sh2) elementwise in place.
//   bf16: flat grid-stride uint4 (no syncs). f32: row-batched read-then-write.
// ---------------------------------------------------------------------------
template<bool F32>
__global__ __launch_bounds__(256) void k4_final(
    const int* __restrict__ flag,
    const float* __restrict__ sc2, const float* __restrict__ sh2,
    void* outp)
{
    if (flag[0] != (F32 ? 1 : 0)) return;
    const int tid = threadIdx.x;

    if (!F32) {
        const size_t NQ = (size_t)ROWS * 200;         // uint4 count
        const size_t stride = (size_t)gridDim.x * blockDim.x;
        size_t q = (size_t)blockIdx.x * blockDim.x + tid;
        const int c0 = ((int)(q & 7)) * 8;            // invariant (stride%8==0)
        float S2[8], H2[8];
        #pragma unroll
        for (int e = 0; e < 8; ++e) { S2[e] = sc2[c0+e]; H2[e] = sh2[c0+e]; }
        u16* z = (u16*)outp;
        for (; q < NQ; q += stride) {
            union { uint4 u4; u16 s[8]; } zv;
            zv.u4 = *(const uint4*)&z[q*8];
            u16 ob[8];
            #pragma unroll
            for (int e = 0; e < 8; ++e) {
                float oo = fmaf(u2h(zv.s[e]), S2[e], H2[e]);
                ob[e] = f2b(oo > 0.0f ? oo : 0.0f);
            }
            *(uint4*)&z[q*8] = *(uint4*)ob;
        }
    } else {
        const int STR = Geo<true>::STR;
        const int c0u = (tid*8) & 63;
        float S2[8], H2[8];
        #pragma unroll
        for (int e = 0; e < 8; ++e) { S2[e] = sc2[c0u+e]; H2[e] = sh2[c0u+e]; }
        const int r0 = blockIdx.x * 10;
        u16* z = (u16*)outp;
        for (int r = 0; r < 10; ++r) {
            const int row = r0 + r;
            uint4 zv;
            if (tid < 200) zv = *(const uint4*)&z[(size_t)row*STR + tid*8];
            __syncthreads();
            if (tid < 200) {
                const u16* zp = (const u16*)&zv;
                float o[8];
                #pragma unroll
                for (int e = 0; e < 8; ++e) {
                    float oo = fmaf(u2h(zp[e]), S2[e], H2[e]);
                    o[e] = oo > 0.0f ? oo : 0.0f;
                }
                float* dst = (float*)outp + (size_t)row*ROWE + tid*8;
                *(float4*)dst     = float4{o[0], o[1], o[2], o[3]};
                *(float4*)(dst+4) = float4{o[4], o[5], o[6], o[7]};
            }
            __syncthreads();
        }
    }
}

// ---------------------------------------------------------------------------
extern "C" void kernel_launch(void* const* d_in, const int* in_sizes, int n_in,
                              void* d_out, int out_size, void* d_ws, size_t ws_size,
                              hipStream_t stream)
{
    const void* x     = d_in[0];
    const void* A     = d_in[1];
    const void* E     = d_in[2];
    const void* W1    = d_in[3];
    const void* b1    = d_in[4];
    const void* W2    = d_in[5];
    const void* b2    = d_in[6];
    const void* W3    = d_in[7];
    const void* b3    = d_in[8];
    const void* Wt    = d_in[9];
    const void* bt    = d_in[10];
    const void* gamma = d_in[11];
    const void* beta  = d_in[12];

    u16* out1 = (u16*)d_out;          // stage-1 staging lives in d_out

    // ws layout — front of d_ws; total ≈ 19.3 MB.
    int*   flag = (int*)d_ws;
    float* wsf  = (float*)d_ws;
    float* bsum = wsf + 4;
    float* sc1  = bsum + 64;
    float* sh1  = sc1 + 64;
    float* sc2  = sh1 + 64;
    float* sh2  = sc2 + 64;
    float* p1   = sh2 + 64;                       // NWID*128
    float* p2   = p1 + (size_t)NWID*128;          // 640*128
    float* q1   = p2 + 640*128;                   // 64*128
    float* q2   = q1 + 64*128;                    // 64*128
    u16*  halo  = (u16*)(q2 + 64*128);            // 5120*1600 u16 = 16.4 MB
    u16*  wcatT = halo + (size_t)5120*1600;       // 13824 f16
    u16*  anf   = wcatT + 13824;                  // 3072 f16
    u16*  wtT   = anf + 3072;                     // 4608 f16

    // host-side dtype dispatch from byte sizes; fallback: launch both variants
    const long NX = (long)B_*T_*V_*C_;            // 3,072,000 elements
    int mode = -1;
    if (n_in > 0) {
        if      (in_sizes[0] == (int)(NX*2)) mode = 0;   // bf16
        else if (in_sizes[0] == (int)(NX*4)) mode = 1;   // f32
    }
    const bool do_b = (mode != 1), do_f = (mode != 0);

    hipLaunchKernelGGL(k0_detect, dim3(1), dim3(256), 0, stream, W1, flag);

    if (do_b) hipLaunchKernelGGL(k1_prep<false>, dim3(1), dim3(256), 0, stream,
                       flag, A, E, W1, W2, W3, Wt, b1, b2, b3, anf, wcatT, wtT, bsum);
    if (do_f) hipLaunchKernelGGL(k1_prep<true>, dim3(1), dim3(256), 0, stream,
                       flag, A, E, W1, W2, W3, Wt, b1, b2, b3, anf, wcatT, wtT, bsum);

    if (do_b) hipLaunchKernelGGL(k2_mfma<false>, dim3(K2BLK), dim3(256), 0, stream,
                       flag, x, wcatT, anf, out1, halo, p1);
    if (do_f) hipLaunchKernelGGL(k2_mfma<true>, dim3(K2BLK), dim3(256), 0, stream,
                       flag, x, wcatT, anf, out1, halo, p1);

    hipLaunchKernelGGL(k_reduce, dim3(64), dim3(128), 0, stream, p1, NWID, q1);

    if (do_b) hipLaunchKernelGGL(k_bnstats<false>, dim3(1), dim3(256), 0, stream,
                       flag, q1, gamma, beta, bsum, 1, sc1, sh1);
    if (do_f) hipLaunchKernelGGL(k_bnstats<true>, dim3(1), dim3(256), 0, stream,
                       flag, q1, gamma, beta, bsum, 1, sc1, sh1);

    if (do_b) hipLaunchKernelGGL(k3_temporal<false>, dim3(10, 64), dim3(256), 0, stream,
                       flag, out1, halo, wtT, bt, sc1, sh1, p2);
    if (do_f) hipLaunchKernelGGL(k3_temporal<true>, dim3(10, 64), dim3(256), 0, stream,
                       flag, out1, halo, wtT, bt, sc1, sh1, p2);

    hipLaunchKernelGGL(k_reduce, dim3(64), dim3(128), 0, stream, p2, 640, q2);

    if (do_b) hipLaunchKernelGGL(k_bnstats<false>, dim3(1), dim3(256), 0, stream,
                       flag, q2, gamma, beta, bsum, 0, sc2, sh2);
    if (do_f) hipLaunchKernelGGL(k_bnstats<true>, dim3(1), dim3(256), 0, stream,
                       flag, q2, gamma, beta, bsum, 0, sc2, sh2);

    if (do_b) hipLaunchKernelGGL(k4_final<false>, dim3(2048), dim3(256), 0, stream,
                       flag, sc2, sh2, d_out);
    if (do_f) hipLaunchKernelGGL(k4_final<true>, dim3(1920), dim3(256), 0, stream,
                       flag, sc2, sh2, d_out);
}

// Round 5
// 428.313 us; speedup vs baseline: 4.6484x; 1.0269x over previous
//
#include <hip/hip_runtime.h>

typedef unsigned short u16;
typedef unsigned int   u32;
typedef _Float16       f16;
typedef _Float16 f16x8 __attribute__((ext_vector_type(8)));
typedef float    f32x4 __attribute__((ext_vector_type(4)));

#define B_  64
#define T_  300
#define V_  25
#define C_  64
#define ROWS (B_*T_)          // 19200
#define ROWE (V_*C_)          // 1600
#define NSTAT 480000.0f       // B*T*V
#define EPS_ 1e-5f
#define TTILE 30              // temporal tile (10 tiles of 30)
#define K2BLK 2400            // k2 blocks (2 batches x 4 rows each)
#define YSP 104               // ys row pad (halfs): 13 granules, 2-way banks

__device__ __forceinline__ float b2f(u16 u) {
    union { u32 i; float f; } v; v.i = ((u32)u) << 16; return v.f;
}
__device__ __forceinline__ u16 f2b(float f) {  // round-to-nearest-even
    union { float f; u32 i; } v; v.f = f;
    u32 x = v.i;
    u32 r = x + 0x7fffu + ((x >> 16) & 1u);
    return (u16)(r >> 16);
}
__device__ __forceinline__ u32 pk2h(float a, float b) {   // pack 2 f32 -> 2 f16
    union { f16 h[2]; u32 u; } p;
    p.h[0] = (f16)a; p.h[1] = (f16)b;
    return p.u;
}
__device__ __forceinline__ u16 h2u(float v) {             // f32 -> f16 bits
    union { f16 h; u16 u; } p; p.h = (f16)v; return p.u;
}
__device__ __forceinline__ float u2h(u16 u) {             // f16 bits -> f32
    union { u16 u; f16 h; } p; p.u = u; return (float)p.h;
}

template<bool F32>
__device__ __forceinline__ float ldv(const void* p, size_t i) {
    if (F32) return ((const float*)p)[i];
    return b2f(((const u16*)p)[i]);
}

// staging row stride in u16 units (fp32 mode: staging row r sits in the
// low half of fp32 output row r's byte range -> in-place overwrite is safe).
template<bool F32> struct Geo { static const int STR = F32 ? 3200 : 1600; };

// ---------------------------------------------------------------------------
// K0: dtype detection (device-side ground truth; host fast-path uses in_sizes)
// ---------------------------------------------------------------------------
__global__ void k0_detect(const void* W1raw, int* flag)
{
    __shared__ float red[256];
    const u16* p = (const u16*)W1raw;
    float mx = 0.0f;
    for (int i = threadIdx.x; i < 4096; i += 256) {
        float v = fabsf(b2f(p[i]));
        if (v == v) mx = fmaxf(mx, v);
    }
    red[threadIdx.x] = mx;
    __syncthreads();
    for (int s = 128; s > 0; s >>= 1) {
        if (threadIdx.x < s) red[threadIdx.x] = fmaxf(red[threadIdx.x], red[threadIdx.x + s]);
        __syncthreads();
    }
    if (threadIdx.x == 0) flag[0] = (red[0] > 1e10f) ? 1 : 0;
}

// ---------------------------------------------------------------------------
// K1: prep tables.
//   anf2 : stacked-An^T fragments (k2 phase-2 B-operand), [ks3][nt2][64][8]:
//          value = An_i[v][u], v=nt*16+(lane&15), u' = ks*32+(lane>>4)*8+j,
//          i=u'>>5, u=u'&31; zero for v>=25 or u>=25.       (3072 f16)
//   wcatT: wcatT[i][c][k(pad 72)] = W_i[k][c], 13824 f16 (k2 phase-1 B).
//   wtT  : wtT[c][k(pad 72)] = Wt[k][c], 4608 f16 (k3 B-operand).
//   bsum : b1+b2+b3 (folded into BN1 mean, NOT added in k2).
// ---------------------------------------------------------------------------
template<bool F32>
__global__ void k1_prep(const int* __restrict__ flag,
                        const void* A, const void* E,
                        const void* W1, const void* W2, const void* W3,
                        const void* Wt,
                        const void* b1, const void* b2, const void* b3,
                        u16* __restrict__ anf2, u16* __restrict__ wcatT,
                        u16* __restrict__ wtT, float* __restrict__ bsum)
{
    if (flag[0] != (F32 ? 1 : 0)) return;
    __shared__ float dinvL[75];
    const int tid = threadIdx.x;
    if (tid < 75) {
        int i = tid / 25, v = tid % 25;
        float d = 1.0f;                       // diagonal forced to 1
        for (int u = 0; u < 25; ++u)
            if (u != v) d += ldv<F32>(A, (i*25+v)*25+u) * ldv<F32>(E, (i*25+v)*25+u);
        dinvL[tid] = (d > 0.0f) ? rsqrtf(d) : 0.0f;
    }
    __syncthreads();
    // stacked An^T fragments
    for (int idx = tid; idx < 3072; idx += 256) {
        int fr = idx >> 9, lane = (idx >> 3) & 63, j = idx & 7;
        int ks = fr >> 1, nt = fr & 1;
        int v  = nt*16 + (lane & 15);
        int up = ks*32 + ((lane >> 4) << 3) + j;
        int i  = up >> 5, u = up & 31;
        float val = 0.0f;
        if (v < 25 && u < 25) {
            float ad = (u == v) ? 1.0f
                     : ldv<F32>(A, (i*25+v)*25+u) * ldv<F32>(E, (i*25+v)*25+u);
            val = dinvL[i*25+v] * ad * dinvL[i*25+u];
        }
        anf2[idx] = h2u(val);
    }
    // WcatT[i][c][k] = W_i[k][c], rows padded to 72 halfs
    for (int idx = tid; idx < 13824; idx += 256) {
        int i = idx / 4608;
        int rem = idx - i*4608;
        int c = rem / 72, k = rem - (rem/72)*72;
        float val = 0.0f;
        if (k < 64) {
            const void* W = (i == 0) ? W1 : ((i == 1) ? W2 : W3);
            val = ldv<F32>(W, k*64 + c);
        }
        wcatT[idx] = h2u(val);
    }
    // WtT[c][k] = Wt[k][c], rows padded to 72 halfs
    for (int idx = tid; idx < 4608; idx += 256) {
        int c = idx / 72, k = idx - (idx/72)*72;
        float val = (k < 64) ? ldv<F32>(Wt, k*64 + c) : 0.0f;
        wtT[idx] = h2u(val);
    }
    if (tid < 64) bsum[tid] = ldv<F32>(b1, tid) + ldv<F32>(b2, tid) + ldv<F32>(b3, tid);
}

// ---------------------------------------------------------------------------
// K2 (MFMA, stacked-K): grid 2400, 256 threads, 2 batches of 4 rows.
//   phase1: Ystack[rr][c][u'] = x @ [W1|W2|W3]; M=112 (4x28-pad), N=192
//     (waves split N: 3 ntiles each), K=64. A-frags straight from global x.
//     D written to ys LDS [rr][c:64][u': 96 pad 104]; stride 104 halfs
//     (13 granules) makes both the b64 writes and b128 reads <=2-way (free).
//   phase2: wave w owns row r0+w: out[c][v] = Ystack_row @ An'^T;
//     M=c (4 tiles), N=v (2 tiles), K=96 (3 frags, hoisted in regs).
//   epilogue: bf16 out1 (+halo rows), BN1 partials (block-reduced).
// ---------------------------------------------------------------------------
template<bool F32>
__global__ __launch_bounds__(256, 3) void k2_mfma(
    const int* __restrict__ flag, const void* x,
    const u16* __restrict__ wcatT, const u16* __restrict__ anf2,
    u16* __restrict__ out1, u16* __restrict__ halo, float* __restrict__ p1)
{
    if (flag[0] != (F32 ? 1 : 0)) return;
    const int STR = Geo<F32>::STR;

    __shared__ f16 ys[4][64*YSP];   // 52 KB (4 planes x 13312 B)

    const int tid = threadIdx.x, lane = tid & 63, w = tid >> 6;
    const int lo = lane & 15, hi = lane >> 4;

    // ---- hoist W fragments (this wave's 3 ntiles) and An' fragments ----
    f16x8 wfr[3][2];
    #pragma unroll
    for (int q = 0; q < 3; ++q)
        #pragma unroll
        for (int kc = 0; kc < 2; ++kc)
            wfr[q][kc] = *(const f16x8*)&wcatT[
                (size_t)((3*w + q)*16 + lo)*72 + kc*32 + (hi << 3)];
    f16x8 anfr[3][2];
    #pragma unroll
    for (int ks = 0; ks < 3; ++ks)
        #pragma unroll
        for (int nt = 0; nt < 2; ++nt)
            anfr[ks][nt] = *(const f16x8*)&anf2[((ks*2 + nt)*64 + lane)*8];

    float ss[16], sq[16];
    #pragma unroll
    for (int i = 0; i < 16; ++i) { ss[i] = 0.0f; sq[i] = 0.0f; }

    #pragma unroll 1
    for (int bb = 0; bb < 2; ++bb) {
        const int r0 = blockIdx.x*8 + bb*4;

        // ---- phase 1: ys[rr][c][u'] = x @ [W1|W2|W3] ----
        #pragma unroll
        for (int mt = 0; mt < 7; ++mt) {
            // A fragment straight from global x
            const int m  = mt*16 + lo;
            const int rA = (m*293) >> 13;            // m/28
            const int uA = m - 28*rA;
            const int ua = (uA < 25) ? uA : 0;       // clamp (pad rows zeroed at D)
            const size_t xb = (size_t)(r0 + rA)*1600 + (size_t)ua*64 + (hi << 3);
            f16x8 a0, a1;
            if (F32) {
                const float* xp = (const float*)x + xb;
                float4 fa = *(const float4*)xp, fb = *(const float4*)(xp + 4);
                a0[0]=(f16)fa.x; a0[1]=(f16)fa.y; a0[2]=(f16)fa.z; a0[3]=(f16)fa.w;
                a0[4]=(f16)fb.x; a0[5]=(f16)fb.y; a0[6]=(f16)fb.z; a0[7]=(f16)fb.w;
                const float* xq = xp + 32;
                float4 ga = *(const float4*)xq, gb = *(const float4*)(xq + 4);
                a1[0]=(f16)ga.x; a1[1]=(f16)ga.y; a1[2]=(f16)ga.z; a1[3]=(f16)ga.w;
                a1[4]=(f16)gb.x; a1[5]=(f16)gb.y; a1[6]=(f16)gb.z; a1[7]=(f16)gb.w;
            } else {
                union { uint4 q4; u16 s[8]; } ta, tb;
                ta.q4 = *(const uint4*)((const u16*)x + xb);
                tb.q4 = *(const uint4*)((const u16*)x + xb + 32);
                #pragma unroll
                for (int e = 0; e < 8; ++e) {
                    a0[e] = (f16)b2f(ta.s[e]);
                    a1[e] = (f16)b2f(tb.s[e]);
                }
            }
            // D row base for the write (per-lane)
            const int md = mt*16 + (hi << 2);
            const int rD = (md*293) >> 13;
            const int u0 = md - 28*rD;               // in {0,4,...,24}
            #pragma unroll
            for (int q = 0; q < 3; ++q) {
                f32x4 d = f32x4{0.f, 0.f, 0.f, 0.f};
                d = __builtin_amdgcn_mfma_f32_16x16x32_f16(a0, wfr[q][0], d, 0, 0, 0);
                d = __builtin_amdgcn_mfma_f32_16x16x32_f16(a1, wfr[q][1], d, 0, 0, 0);
                const int np = (3*w + q)*16 + lo;
                const int ib = np >> 6, cb = np & 63;
                f16* yr = &ys[rD][cb*YSP + ib*32 + u0];
                if (u0 <= 20) {
                    *(uint2*)yr = make_uint2(pk2h(d[0], d[1]), pk2h(d[2], d[3]));
                } else {  // u0 == 24: valid half + zero pad u' 25..31
                    *(uint4*)yr = make_uint4(pk2h(d[0], 0.0f), 0u, 0u, 0u);
                }
            }
        }
        __syncthreads();

        // ---- phase 2: wave w -> row r0+w : out[c][v] = Ystack @ An'^T ----
        f32x4 acc[4][2];
        #pragma unroll
        for (int mt = 0; mt < 4; ++mt) {
            acc[mt][0] = f32x4{0.f,0.f,0.f,0.f};
            acc[mt][1] = f32x4{0.f,0.f,0.f,0.f};
        }
        #pragma unroll
        for (int ks = 0; ks < 3; ++ks) {
            #pragma unroll
            for (int mt = 0; mt < 4; ++mt) {
                f16x8 a = *(const f16x8*)&ys[w][
                    (mt*16 + lo)*YSP + ks*32 + (hi << 3)];
                acc[mt][0] = __builtin_amdgcn_mfma_f32_16x16x32_f16(a, anfr[ks][0], acc[mt][0], 0, 0, 0);
                acc[mt][1] = __builtin_amdgcn_mfma_f32_16x16x32_f16(a, anfr[ks][1], acc[mt][1], 0, 0, 0);
            }
        }

        // ---- epilogue: out1 (+halo), BN1 partial accumulation ----
        {
            const int row = r0 + w;
            const int b = row / T_;
            const int t = row - b*T_;
            const int tm = t % TTILE;
            const bool hbd = (tm < 4) || (tm >= TTILE - 4);
            u16* hrow = nullptr;
            if (hbd) {
                const int slot = tm < 4 ? tm : tm - 22;
                hrow = halo + (((size_t)b*10 + t/TTILE)*8 + slot)*ROWE;
            }
            u16* orow = out1 + (size_t)row*STR;
            #pragma unroll
            for (int mt = 0; mt < 4; ++mt) {
                const int c0 = mt*16 + (hi << 2);
                #pragma unroll
                for (int nt = 0; nt < 2; ++nt) {
                    const int v = nt*16 + lo;
                    if (v < 25) {
                        const float o0 = acc[mt][nt][0];
                        const float o1 = acc[mt][nt][1];
                        const float o2 = acc[mt][nt][2];
                        const float o3 = acc[mt][nt][3];
                        ss[mt*4+0] += o0; sq[mt*4+0] += o0*o0;
                        ss[mt*4+1] += o1; sq[mt*4+1] += o1*o1;
                        ss[mt*4+2] += o2; sq[mt*4+2] += o2*o2;
                        ss[mt*4+3] += o3; sq[mt*4+3] += o3*o3;
                        ushort4 pk;
                        pk.x = f2b(o0); pk.y = f2b(o1); pk.z = f2b(o2); pk.w = f2b(o3);
                        *(ushort4*)&orow[v*64 + c0] = pk;
                        if (hbd) *(ushort4*)&hrow[v*64 + c0] = pk;
                    }
                }
            }
        }
        __syncthreads();   // ys reads done before next batch overwrites
    }

    // ---- BN1 partials: lane-reduce, then block-reduce via ys scratch ----
    #pragma unroll
    for (int si = 0; si < 16; ++si) {
        #pragma unroll
        for (int off = 1; off < 16; off <<= 1) {
            ss[si] += __shfl_xor(ss[si], off);
            sq[si] += __shfl_xor(sq[si], off);
        }
    }
    float* red = (float*)ys;     // 512 floats; ys free after last barrier
    if (lo == 0) {
        #pragma unroll
        for (int si = 0; si < 16; ++si) {
            const int c = ((si >> 2) << 4) + (hi << 2) + (si & 3);
            red[w*64 + c]        = ss[si];
            red[256 + w*64 + c]  = sq[si];
        }
    }
    __syncthreads();
    if (tid < 128) {
        const int isq = tid >> 6, c = tid & 63;
        const float* rb = red + isq*256;
        p1[(size_t)blockIdx.x*128 + isq*64 + c] =
            rb[c] + rb[64 + c] + rb[128 + c] + rb[192 + c];
    }
}

// ---------------------------------------------------------------------------
// K_reduce: parallel partial-sum reduce part[n][128] -> q[64][128]. dtype-free.
// ---------------------------------------------------------------------------
__global__ __launch_bounds__(128) void k_reduce(const float* __restrict__ in,
                                                int n, float* __restrict__ outq)
{
    const int t = threadIdx.x;
    float s = 0.0f;
    for (int r = blockIdx.x; r < n; r += 64) s += in[(size_t)r*128 + t];
    outq[(size_t)blockIdx.x*128 + t] = s;
}

// ---------------------------------------------------------------------------
// K_bnstats: finalize from q[64][128]. useb: add mb[c] to the mean (bias fold).
// ---------------------------------------------------------------------------
template<bool F32>
__global__ void k_bnstats(const int* __restrict__ flag,
                          const float* __restrict__ q,
                          const void* gamma, const void* beta,
                          const float* __restrict__ mb, int useb,
                          float* __restrict__ scale, float* __restrict__ shift)
{
    if (flag[0] != (F32 ? 1 : 0)) return;
    __shared__ float redL[512];
    const int tid = threadIdx.x, c = tid & 63, g = tid >> 6;   // g < 4
    float s = 0.0f, ssq = 0.0f;
    for (int r = g; r < 64; r += 4) { s += q[r*128 + c]; ssq += q[r*128 + 64 + c]; }
    redL[g*64 + c] = s; redL[256 + g*64 + c] = ssq;
    __syncthreads();
    if (tid < 64) {
        const float S  = redL[tid] + redL[64+tid] + redL[128+tid] + redL[192+tid];
        const float SS = redL[256+tid] + redL[320+tid] + redL[384+tid] + redL[448+tid];
        const float my  = S / NSTAT;                 // mean of y (bias-free)
        const float var = SS / NSTAT - my*my;        // var(y+b) == var(y)
        const float m   = my + (useb ? mb[tid] : 0.0f);
        const float rstd = rsqrtf(var + EPS_);
        const float sc = ldv<F32>(gamma, tid) * rstd;
        scale[tid] = sc;
        shift[tid] = ldv<F32>(beta, tid) - m * sc;
    }
}

template<bool F32>
__device__ __forceinline__ const u16* row_ptr(const u16* out1, const u16* halo,
                                              int b, int s, int t0)
{
    if (s >= t0 && s < t0 + TTILE)
        return &out1[((size_t)b*T_ + s) * Geo<F32>::STR];
    const int tile = s / TTILE, rem = s % TTILE;
    const int slot = rem < 4 ? rem : rem - 22;
    return &halo[(((size_t)b*10 + tile)*8 + slot) * ROWE];
}

// ---------------------------------------------------------------------------
// K3_temporal (fused, single pass): per block one b, tile of 30 t's.
// ---------------------------------------------------------------------------
template<bool F32>
__global__ __launch_bounds__(256, 3) void k3_temporal(
    const int* __restrict__ flag,
    u16* out1, const u16* __restrict__ halo,
    const u16* __restrict__ wtT, const void* bt,
    const float* __restrict__ sc1, const float* __restrict__ sh1,
    float* __restrict__ p2)
{
    if (flag[0] != (F32 ? 1 : 0)) return;
    const int STR = Geo<F32>::STR;

    __shared__ u16   ring[10*1600];     // h rows (bf16), 32 KB
    __shared__ f16   hsumH[32*72];      // hsum f16, A-operand layout, 4.6 KB
    __shared__ u16   zL[1600];          // z row (f16), 3.2 KB
    __shared__ float redL[256];

    const int tid = threadIdx.x, lane = tid & 63, w = tid >> 6;
    const int b = blockIdx.y, t0 = blockIdx.x * TTILE;
    const bool act = (tid < 200);

    // zero hsumH pad rows 25..31
    for (int i = tid; i < 252; i += 256) ((u32*)&hsumH[25*72])[i] = 0u;

    float hacc[8];
    #pragma unroll
    for (int e = 0; e < 8; ++e) hacc[e] = 0.0f;
    const int c0u = (tid*8) & 63;
    const int vrow = tid >> 3;
    float S1[8], H1[8];
    #pragma unroll
    for (int e = 0; e < 8; ++e) { S1[e] = sc1[c0u+e]; H1[e] = sh1[c0u+e]; }

    const int ntp = w >> 1, mt = w & 1;
    f16x8 wfr[2][2];
    #pragma unroll
    for (int ntl = 0; ntl < 2; ++ntl)
        #pragma unroll
        for (int ks = 0; ks < 2; ++ks)
            wfr[ntl][ks] = *(const f16x8*)&wtT[
                ((ntp*2+ntl)*16 + (lane & 15))*72 + ks*32 + ((lane >> 4) << 3)];
    float btv[2];
    #pragma unroll
    for (int ntl = 0; ntl < 2; ++ntl)
        btv[ntl] = ldv<F32>(bt, (ntp*2+ntl)*16 + (lane & 15));

    {   // initial window [t0-4, t0+4]
        int slo = t0 - 4; if (slo < 0) slo = 0;
        for (int s = slo; s <= t0 + 4; ++s) {
            const u16* xr = row_ptr<F32>(out1, halo, b, s, t0);
            if (act) {
                uint4 xv = *(const uint4*)&xr[tid*8];
                const u16* xs = (const u16*)&xv;
                u16 hb[8];
                #pragma unroll
                for (int e = 0; e < 8; ++e) {
                    float hv = fmaf(b2f(xs[e]), S1[e], H1[e]);
                    hv = hv > 0.0f ? hv : 0.0f;
                    hb[e] = f2b(hv);
                    hacc[e] += b2f(hb[e]);
                }
                *(uint4*)&ring[(s%10)*1600 + tid*8] = *(uint4*)hb;
            }
        }
        if (act) {
            u16 hs[8];
            #pragma unroll
            for (int e = 0; e < 8; ++e) hs[e] = h2u(hacc[e]);
            *(uint4*)&hsumH[vrow*72 + c0u] = *(uint4*)hs;
        }
    }
    __syncthreads();

    float zs[2] = {0.f, 0.f}, zq[2] = {0.f, 0.f};

    for (int t = t0; t < t0 + TTILE; ++t) {
        {   // phase M: z = hsum @ Wt + bt (MFMA), stats, stage z
            const int arow = (mt*16 + (lane & 15))*72 + ((lane >> 4) << 3);
            f16x8 a0 = *(const f16x8*)&hsumH[arow];
            f16x8 a1 = *(const f16x8*)&hsumH[arow + 32];
            #pragma unroll
            for (int ntl = 0; ntl < 2; ++ntl) {
                f32x4 d = f32x4{btv[ntl], btv[ntl], btv[ntl], btv[ntl]};
                d = __builtin_amdgcn_mfma_f32_16x16x32_f16(a0, wfr[ntl][0], d, 0, 0, 0);
                d = __builtin_amdgcn_mfma_f32_16x16x32_f16(a1, wfr[ntl][1], d, 0, 0, 0);
                const int cc = (ntp*2+ntl)*16 + (lane & 15);
                #pragma unroll
                for (int j = 0; j < 4; ++j) {
                    const int v = mt*16 + ((lane >> 4) << 2) + j;
                    if (v < 25) {
                        zs[ntl] += d[j]; zq[ntl] += d[j]*d[j];
                        zL[v*64 + cc] = h2u(d[j]);
                    }
                }
            }
        }
        __syncthreads();

        if (tid < 200)
            *(uint4*)&out1[((size_t)b*T_ + t)*STR + tid*8] = ((const uint4*)zL)[tid];

        if (t + 1 < t0 + TTILE) {
            const int snew = t + 5, sold = t - 4;
            if (act) {
                if (snew < T_) {
                    const u16* xr = row_ptr<F32>(out1, halo, b, snew, t0);
                    uint4 xv = *(const uint4*)&xr[tid*8];
                    const u16* xs = (const u16*)&xv;
                    u16 hb[8];
                    #pragma unroll
                    for (int e = 0; e < 8; ++e) {
                        float hv = fmaf(b2f(xs[e]), S1[e], H1[e]);
                        hv = hv > 0.0f ? hv : 0.0f;
                        hb[e] = f2b(hv);
                        hacc[e] += b2f(hb[e]);
                    }
                    *(uint4*)&ring[(snew%10)*1600 + tid*8] = *(uint4*)hb;
                }
                if (sold >= 0) {
                    uint4 ov = *(const uint4*)&ring[(sold%10)*1600 + tid*8];
                    const u16* os = (const u16*)&ov;
                    #pragma unroll
                    for (int e = 0; e < 8; ++e) hacc[e] -= b2f(os[e]);
                }
                u16 hs[8];
                #pragma unroll
                for (int e = 0; e < 8; ++e) hs[e] = h2u(hacc[e]);
                *(uint4*)&hsumH[vrow*72 + c0u] = *(uint4*)hs;
            }
        }
        __syncthreads();
    }

    #pragma unroll
    for (int ntl = 0; ntl < 2; ++ntl) {
        #pragma unroll
        for (int off = 16; off < 64; off <<= 1) {
            zs[ntl] += __shfl_xor(zs[ntl], off);
            zq[ntl] += __shfl_xor(zq[ntl], off);
        }
    }
    if (lane < 16) {
        redL[w*32 + lane]            = zs[0];
        redL[w*32 + 16 + lane]       = zs[1];
        redL[128 + w*32 + lane]      = zq[0];
        redL[128 + w*32 + 16 + lane] = zq[1];
    }
    __syncthreads();
    if (tid < 64) {
        const int c = tid;
        const int ntg = c >> 4, pr = ntg >> 1, ntl = ntg & 1, l = c & 15;
        const int w0 = pr*2, w1 = pr*2 + 1;
        float s = redL[w0*32 + ntl*16 + l] + redL[w1*32 + ntl*16 + l];
        float q = redL[128 + w0*32 + ntl*16 + l] + redL[128 + w1*32 + ntl*16 + l];
        const int blk = blockIdx.y * (T_/TTILE) + blockIdx.x;
        p2[(size_t)blk*128 + c]      = s;
        p2[(size_t)blk*128 + 64 + c] = q;
    }
}

// ---------------------------------------------------------------------------
// K4_final: out = relu(z*sc2 + sh2) elementwise in place.
// ---------------------------------------------------------------------------
template<bool F32>
__global__ __launch_bounds__(256) void k4_final(
    const int* __restrict__ flag,
    const float* __restrict__ sc2, const float* __restrict__ sh2,
    void* outp)
{
    if (flag[0] != (F32 ? 1 : 0)) return;
    const int tid = threadIdx.x;

    if (!F32) {
        const size_t NQ = (size_t)ROWS * 200;         // uint4 count
        const size_t stride = (size_t)gridDim.x * blockDim.x;
        size_t q = (size_t)blockIdx.x * blockDim.x + tid;
        const int c0 = ((int)(q & 7)) * 8;            // invariant (stride%8==0)
        float S2[8], H2[8];
        #pragma unroll
        for (int e = 0; e < 8; ++e) { S2[e] = sc2[c0+e]; H2[e] = sh2[c0+e]; }
        u16* z = (u16*)outp;
        for (; q < NQ; q += stride) {
            union { uint4 u4; u16 s[8]; } zv;
            zv.u4 = *(const uint4*)&z[q*8];
            u16 ob[8];
            #pragma unroll
            for (int e = 0; e < 8; ++e) {
                float oo = fmaf(u2h(zv.s[e]), S2[e], H2[e]);
                ob[e] = f2b(oo > 0.0f ? oo : 0.0f);
            }
            *(uint4*)&z[q*8] = *(uint4*)ob;
        }
    } else {
        const int STR = Geo<true>::STR;
        const int c0u = (tid*8) & 63;
        float S2[8], H2[8];
        #pragma unroll
        for (int e = 0; e < 8; ++e) { S2[e] = sc2[c0u+e]; H2[e] = sh2[c0u+e]; }
        const int r0 = blockIdx.x * 10;
        u16* z = (u16*)outp;
        for (int r = 0; r < 10; ++r) {
            const int row = r0 + r;
            uint4 zv;
            if (tid < 200) zv = *(const uint4*)&z[(size_t)row*STR + tid*8];
            __syncthreads();
            if (tid < 200) {
                const u16* zp = (const u16*)&zv;
                float o[8];
                #pragma unroll
                for (int e = 0; e < 8; ++e) {
                    float oo = fmaf(u2h(zp[e]), S2[e], H2[e]);
                    o[e] = oo > 0.0f ? oo : 0.0f;
                }
                float* dst = (float*)outp + (size_t)row*ROWE + tid*8;
                *(float4*)dst     = float4{o[0], o[1], o[2], o[3]};
                *(float4*)(dst+4) = float4{o[4], o[5], o[6], o[7]};
            }
            __syncthreads();
        }
    }
}

// ---------------------------------------------------------------------------
extern "C" void kernel_launch(void* const* d_in, const int* in_sizes, int n_in,
                              void* d_out, int out_size, void* d_ws, size_t ws_size,
                              hipStream_t stream)
{
    const void* x     = d_in[0];
    const void* A     = d_in[1];
    const void* E     = d_in[2];
    const void* W1    = d_in[3];
    const void* b1    = d_in[4];
    const void* W2    = d_in[5];
    const void* b2    = d_in[6];
    const void* W3    = d_in[7];
    const void* b3    = d_in[8];
    const void* Wt    = d_in[9];
    const void* bt    = d_in[10];
    const void* gamma = d_in[11];
    const void* beta  = d_in[12];

    u16* out1 = (u16*)d_out;          // stage-1 staging lives in d_out

    // ws layout — front of d_ws; total ≈ 18.1 MB.
    int*   flag = (int*)d_ws;
    float* wsf  = (float*)d_ws;
    float* bsum = wsf + 4;
    float* sc1  = bsum + 64;
    float* sh1  = sc1 + 64;
    float* sc2  = sh1 + 64;
    float* sh2  = sc2 + 64;
    float* p1   = sh2 + 64;                       // K2BLK*128
    float* p2   = p1 + (size_t)K2BLK*128;         // 640*128
    float* q1   = p2 + 640*128;                   // 64*128
    float* q2   = q1 + 64*128;                    // 64*128
    u16*  halo  = (u16*)(q2 + 64*128);            // 5120*1600 u16 = 16.4 MB
    u16*  wcatT = halo + (size_t)5120*1600;       // 13824 f16
    u16*  anf2  = wcatT + 13824;                  // 3072 f16
    u16*  wtT   = anf2 + 3072;                    // 4608 f16

    // host-side dtype dispatch from byte sizes; fallback: launch both variants
    const long NX = (long)B_*T_*V_*C_;            // 3,072,000 elements
    int mode = -1;
    if (n_in > 0) {
        if      (in_sizes[0] == (int)(NX*2)) mode = 0;   // bf16
        else if (in_sizes[0] == (int)(NX*4)) mode = 1;   // f32
    }
    const bool do_b = (mode != 1), do_f = (mode != 0);

    hipLaunchKernelGGL(k0_detect, dim3(1), dim3(256), 0, stream, W1, flag);

    if (do_b) hipLaunchKernelGGL(k1_prep<false>, dim3(1), dim3(256), 0, stream,
                       flag, A, E, W1, W2, W3, Wt, b1, b2, b3, anf2, wcatT, wtT, bsum);
    if (do_f) hipLaunchKernelGGL(k1_prep<true>, dim3(1), dim3(256), 0, stream,
                       flag, A, E, W1, W2, W3, Wt, b1, b2, b3, anf2, wcatT, wtT, bsum);

    if (do_b) hipLaunchKernelGGL(k2_mfma<false>, dim3(K2BLK), dim3(256), 0, stream,
                       flag, x, wcatT, anf2, out1, halo, p1);
    if (do_f) hipLaunchKernelGGL(k2_mfma<true>, dim3(K2BLK), dim3(256), 0, stream,
                       flag, x, wcatT, anf2, out1, halo, p1);

    hipLaunchKernelGGL(k_reduce, dim3(64), dim3(128), 0, stream, p1, K2BLK, q1);

    if (do_b) hipLaunchKernelGGL(k_bnstats<false>, dim3(1), dim3(256), 0, stream,
                       flag, q1, gamma, beta, bsum, 1, sc1, sh1);
    if (do_f) hipLaunchKernelGGL(k_bnstats<true>, dim3(1), dim3(256), 0, stream,
                       flag, q1, gamma, beta, bsum, 1, sc1, sh1);

    if (do_b) hipLaunchKernelGGL(k3_temporal<false>, dim3(10, 64), dim3(256), 0, stream,
                       flag, out1, halo, wtT, bt, sc1, sh1, p2);
    if (do_f) hipLaunchKernelGGL(k3_temporal<true>, dim3(10, 64), dim3(256), 0, stream,
                       flag, out1, halo, wtT, bt, sc1, sh1, p2);

    hipLaunchKernelGGL(k_reduce, dim3(64), dim3(128), 0, stream, p2, 640, q2);

    if (do_b) hipLaunchKernelGGL(k_bnstats<false>, dim3(1), dim3(256), 0, stream,
                       flag, q2, gamma, beta, bsum, 0, sc2, sh2);
    if (do_f) hipLaunchKernelGGL(k_bnstats<true>, dim3(1), dim3(256), 0, stream,
                       flag, q2, gamma, beta, bsum, 0, sc2, sh2);

    if (do_b) hipLaunchKernelGGL(k4_final<false>, dim3(2048), dim3(256), 0, stream,
                       flag, sc2, sh2, d_out);
    if (do_f) hipLaunchKernelGGL(k4_final<true>, dim3(1920), dim3(256), 0, stream,
                       flag, sc2, sh2, d_out);
}